// Round 8
// baseline (1103.119 us; speedup 1.0000x reference)
//
#include <hip/hip_runtime.h>
#include <hip/hip_bf16.h>

// SocialLSTM forward, MI355X gfx950.
// Dual-dtype: float inputs may be bf16 or f32; detected at runtime from W_soc.
// ws layout (bytes):
//   h_ws  f32[1024*64]      @ 0
//   c_ws  f32[1024*64]      @ 262144
//   Wt2   bf16[64][256][64] @ 1835008   (W_soc cell-major: [cell][n][k], 2 MB)
//   Hbuf  bf16[1024*3136]   @ 3932160   (49 reachable cells * 64 hid per row)
//   flag  int32             @ 11141120  (0 = bf16 inputs, 1 = f32 inputs)
//   part  f32[8][1024*256]  @ 16777216  (K-split GEMM partials, no atomics)
//   r_all f32[32][1024][64] @ 33554432  (precomputed r = relu(coords@Wemb+b))
//   offs  u16[32*1024][64]  @ 41943040  (per (t,i): 50 prefix offsets of cell lists)
//   ents  u16[32*1024][1024]@ 50331648  (per (t,i): compacted neighbor j-lists)

typedef short bf16x8 __attribute__((ext_vector_type(8)));
typedef float f32x4 __attribute__((ext_vector_type(4)));

__device__ __forceinline__ float u2f(unsigned short u) {
    union { unsigned int i; float f; } v; v.i = ((unsigned int)u) << 16; return v.f;
}
__device__ __forceinline__ unsigned short f2b(float f) {
    __hip_bfloat16 hb = __float2bfloat16(f);
    return *(unsigned short*)&hb;
}
__device__ __forceinline__ float ldin(const void* p, int idx, int isf32) {
    return isf32 ? ((const float*)p)[idx] : u2f(((const unsigned short*)p)[idx]);
}
__device__ __forceinline__ int get_tpred(const int* p) {
    int v = p[0];
    if (v >= 0 && v <= 64) return v;
    float f = ((const float*)p)[0];
    if (f >= 0.f && f <= 64.f) return (int)f;
    float g = u2f(((const unsigned short*)p)[0]);
    if (g >= 0.f && g <= 64.f) return (int)g;
    return 31;
}

// ---------------- dtype detector: bf16-decode W_soc, look for huge/NaN -----
__global__ __launch_bounds__(256) void k_detect(const void* __restrict__ Wsoc,
                                                int* __restrict__ flag) {
    __shared__ int f;
    int tid = threadIdx.x;
    if (tid == 0) f = 0;
    __syncthreads();
    const unsigned short* p = (const unsigned short*)Wsoc;
    #pragma unroll
    for (int k = 0; k < 4; k++) {
        float v = u2f(p[tid * 4 + k]);
        if (!(v == v) || fabsf(v) > 1e20f) f = 1;   // same-address LDS write, benign
    }
    __syncthreads();
    if (tid == 0) flag[0] = f;
}

// ------- one-time: W_soc (4096x256) -> Wt2 bf16 cell-major [cell][n][k] ----
__global__ __launch_bounds__(256) void k_transpose(const void* __restrict__ Wsoc,
                                                   unsigned short* __restrict__ Wt2,
                                                   const int* __restrict__ flag) {
    __shared__ __align__(16) unsigned short tile[32 * 264];
    int isf32 = flag[0];
    int b = blockIdx.x, tid = threadIdx.x;
    int k0 = b * 32;
    if (isf32) {
        const float* W = (const float*)Wsoc;
        #pragma unroll
        for (int p = 0; p < 4; p++) {
            int kk = (tid >> 5) + p * 8;
            int n8 = (tid & 31) * 8;
            #pragma unroll
            for (int q = 0; q < 8; q++)
                tile[kk * 264 + n8 + q] = f2b(W[(k0 + kk) * 256 + n8 + q]);
        }
    } else {
        const unsigned short* W = (const unsigned short*)Wsoc;
        #pragma unroll
        for (int p = 0; p < 4; p++) {
            int kk = (tid >> 5) + p * 8;
            int n8 = (tid & 31) * 8;
            *(uint4*)&tile[kk * 264 + n8] = *(const uint4*)(W + (k0 + kk) * 256 + n8);
        }
    }
    __syncthreads();
    int n = tid;
    unsigned int packed[16];
    #pragma unroll
    for (int q = 0; q < 16; q++) {
        unsigned int lo = tile[(2 * q) * 264 + n];
        unsigned int hi = tile[(2 * q + 1) * 264 + n];
        packed[q] = lo | (hi << 16);
    }
    int craw = k0 >> 6, kk0 = k0 & 63;
    uint4* dst = (uint4*)(Wt2 + (long)craw * 16384 + (long)n * 64 + kk0);
    #pragma unroll
    for (int p = 0; p < 4; p++)
        dst[p] = make_uint4(packed[4*p], packed[4*p+1], packed[4*p+2], packed[4*p+3]);
}

// ---------------- one-time: zero d_out (dtype-sized), h0/c0 -> f32 ---------
__global__ __launch_bounds__(256) void k_init(void* __restrict__ out,
                                              const void* __restrict__ hin,
                                              const void* __restrict__ cin,
                                              float* __restrict__ h_ws,
                                              float* __restrict__ c_ws,
                                              const int* __restrict__ flag) {
    int isf32 = flag[0];
    int b = blockIdx.x, tid = threadIdx.x;
    if (b < 16) {
        uint4 z = make_uint4(0u, 0u, 0u, 0u);
        uint4* p = (uint4*)out;
        int n16 = isf32 ? 16384 : 8192;          // 65536 elems * 4 or 2 bytes / 16
        for (int idx = b * 256 + tid; idx < n16; idx += 4096) p[idx] = z;
    } else {
        int sb = b - 16;
        const void* src = (sb < 16) ? hin : cin;
        float* dst = (sb < 16) ? h_ws : c_ws;
        sb &= 15;
        int base = (sb * 256 + tid) * 16;
        #pragma unroll
        for (int p = 0; p < 16; p++) dst[base + p] = ldin(src, base + p, isf32);
    }
}

// ---------------- one-time: codes, 4 agents/block, LDS-staged coords -------
// grid 8192: t = bid>>8, agents i = (bid&255)*4 .. +3. (R7-verified; equal
// time to R4 variant with 2x lower FETCH.)
__global__ __launch_bounds__(256) void k_codes(const void* __restrict__ X,
                                               const int* __restrict__ masks,
                                               const void* __restrict__ Wemb,
                                               const void* __restrict__ bemb,
                                               const int* __restrict__ Tpred,
                                               const int* __restrict__ flag,
                                               float* __restrict__ r_all,
                                               unsigned short* __restrict__ offs,
                                               unsigned short* __restrict__ ents) {
    int bid = blockIdx.x;
    int t = bid >> 8, ig = bid & 255;
    if (t > get_tpred(Tpred)) return;
    int isf32 = flag[0];
    int tid = threadIdx.x;
    __shared__ float sx[1024], sy[1024];
    __shared__ unsigned char sm[1024];
    __shared__ int cnt[49];
    __shared__ unsigned short off_s[52];
    const int* mrow = masks + t * 1024;
    #pragma unroll
    for (int p = 0; p < 4; p++) {
        int j = tid + p * 256;
        sm[j] = (unsigned char)(mrow[j] != 0);
        float x, y;
        if (isf32) {
            float2 xy = *(const float2*)((const float*)X + ((long)(t * 1024 + j)) * 4 + 2);
            x = xy.x; y = xy.y;
        } else {
            unsigned int u = *(const unsigned int*)((const unsigned short*)X + ((long)(t * 1024 + j)) * 4 + 2);
            x = u2f((unsigned short)(u & 0xFFFF));
            y = u2f((unsigned short)(u >> 16));
        }
        sx[j] = x; sy[j] = y;
    }
    __syncthreads();
    {   // r = relu(coords@Wemb + bemb) for the 4 agents (thread a=tid>>6,u=tid&63)
        int a = tid >> 6, u = tid & 63;
        int i = ig * 4 + a;
        float v = ldin(Wemb, u, isf32) * sx[i] + ldin(Wemb, 64 + u, isf32) * sy[i]
                + ldin(bemb, u, isf32);
        r_all[((long)t * 1024 + i) * 64 + u] = fmaxf(v, 0.f);
    }
    for (int a = 0; a < 4; a++) {
        int i = ig * 4 + a;
        if (!sm[i]) continue;                 // block-uniform; lists unused
        if (tid < 49) cnt[tid] = 0;
        __syncthreads();
        int cc[4], rk[4];
        float cix = sx[i], ciy = sy[i];
        #pragma unroll
        for (int p = 0; p < 4; p++) {
            int j = tid + p * 256;
            cc[p] = -1;
            if (j != i && sm[j]) {
                float dx = sx[j] - cix, dy = sy[j] - ciy;
                int g0 = (int)dx, g1 = (int)dy;   // trunc toward zero == jnp.trunc
                if (g0 >= -3 && g0 <= 3 && g1 >= -3 && g1 <= 3) {
                    int c = (g0 + 3) * 7 + (g1 + 3);      // dense 0..48
                    cc[p] = c;
                    rk[p] = atomicAdd(&cnt[c], 1);
                }
            }
        }
        __syncthreads();
        if (tid == 0) {
            int o = 0;
            #pragma unroll 1
            for (int c = 0; c < 49; c++) { off_s[c] = (unsigned short)o; o += cnt[c]; }
            off_s[49] = (unsigned short)o;
        }
        __syncthreads();
        unsigned short* eb = ents + ((long)t * 1024 + i) * 1024;
        #pragma unroll
        for (int p = 0; p < 4; p++)
            if (cc[p] >= 0)
                eb[off_s[cc[p]] + rk[p]] = (unsigned short)(tid + p * 256);
        if (tid < 50) offs[((long)t * 1024 + i) * 64 + tid] = off_s[tid];
    }
}

// ---------------- per step: pure gather-accumulate pooling -> Hbuf ---------
// 1024 blocks (one per agent) keeps ~16 waves/CU of independent gather work
// in flight — this phase is latency-bound, parallelism is the currency.
// (R4-verified fastest variant.)
__global__ __launch_bounds__(256) void k_pool(const int* __restrict__ masks,
                                              const int* __restrict__ Tpred,
                                              const float* __restrict__ h_ws,
                                              const unsigned short* __restrict__ offs,
                                              const unsigned short* __restrict__ ents,
                                              unsigned short* __restrict__ Hbuf,
                                              int t) {
    if (t > get_tpred(Tpred)) return;
    int i = blockIdx.x, tid = threadIdx.x;
    long hb_base = (long)i * 3136;
    if (masks[t * 1024 + i] == 0) {   // block-uniform: H row is all zeros
        unsigned int* hp = (unsigned int*)(Hbuf + hb_base);
        for (int idx = tid; idx < 1568; idx += 256) hp[idx] = 0u;
        return;
    }
    __shared__ __align__(16) unsigned short el[1024];
    __shared__ unsigned short of[52];
    if (tid < 50) of[tid] = offs[((long)t * 1024 + i) * 64 + tid];
    {
        const uint4* src = (const uint4*)(ents + ((long)t * 1024 + i) * 1024);
        uint4* dst = (uint4*)el;
        if (tid < 128) dst[tid] = src[tid];   // stage full list; tail garbage unread
    }
    __syncthreads();
    int w = tid >> 6, lane = tid & 63;
    for (int c = w; c < 49; c += 4) {       // round-robin cells over 4 waves
        int k = of[c], n = of[c + 1];
        float acc = 0.f;
        for (; k + 8 <= n; k += 8) {        // 8 loads in flight per group
            int j0 = el[k], j1 = el[k + 1], j2 = el[k + 2], j3 = el[k + 3];
            int j4 = el[k + 4], j5 = el[k + 5], j6 = el[k + 6], j7 = el[k + 7];
            float v0 = h_ws[j0 * 64 + lane];
            float v1 = h_ws[j1 * 64 + lane];
            float v2 = h_ws[j2 * 64 + lane];
            float v3 = h_ws[j3 * 64 + lane];
            float v4 = h_ws[j4 * 64 + lane];
            float v5 = h_ws[j5 * 64 + lane];
            float v6 = h_ws[j6 * 64 + lane];
            float v7 = h_ws[j7 * 64 + lane];
            acc += ((v0 + v1) + (v2 + v3)) + ((v4 + v5) + (v6 + v7));
        }
        for (; k < n; k++) acc += h_ws[el[k] * 64 + lane];
        Hbuf[hb_base + c * 64 + lane] = f2b(acc);
    }
}

// ---------------- per step: part[s] = H @ W_soc slice (MFMA, dbuf LDS) -----
// grid 512: ch = bid&3 (64-col slice), s = (bid>>2)&7 (K-split), rb = bid>>5.
// B-tile staged from cell-major Wt2: fully contiguous per cell. (R4-verified.)
__global__ __launch_bounds__(256) void k_gemm(const unsigned short* __restrict__ Hbuf,
                                              const unsigned short* __restrict__ Wt2,
                                              const int* __restrict__ Tpred,
                                              float* __restrict__ part,
                                              int t) {
    if (t > get_tpred(Tpred)) return;
    int bid = blockIdx.x, tid = threadIdx.x;
    int ch = bid & 3, s = (bid >> 2) & 7, rb = bid >> 5;
    int row0 = rb * 64, col0 = ch * 64;
    int m0 = (49 * s) >> 3, m1 = (49 * (s + 1)) >> 3;   // 6,6,6,6,6,6,6,7 cells
    __shared__ __align__(16) short Asm[2][64 * 72];   // double-buffered
    __shared__ __align__(16) short Bsm[2][64 * 72];
    int w = tid >> 6, lane = tid & 63;
    int wrow = (w & 1) * 32, wcol = (w >> 1) * 32;
    int mrow = lane & 15, q = lane >> 4;
    int row = tid >> 2, seg = tid & 3;
    const unsigned short* Arow = Hbuf + (long)(row0 + row) * 3136;
    const long boff = (long)(col0 + row) * 64;
    f32x4 acc[2][2];
    f32x4 zz = {0.f, 0.f, 0.f, 0.f};
    #pragma unroll
    for (int a = 0; a < 2; a++)
        #pragma unroll
        for (int b = 0; b < 2; b++) acc[a][b] = zz;
    uint4 ra0, ra1, rb0, rb1;
    {   // prologue: load cell m0
        int craw = ((m0 / 7) * 8 + (m0 % 7) + 9);
        const unsigned short* Bc = Wt2 + (long)craw * 16384 + boff;
        ra0 = *(const uint4*)(Arow + m0 * 64 + seg * 8);
        ra1 = *(const uint4*)(Arow + m0 * 64 + (seg + 4) * 8);
        rb0 = *(const uint4*)(Bc + seg * 8);
        rb1 = *(const uint4*)(Bc + (seg + 4) * 8);
        *(uint4*)&Asm[0][row * 72 + seg * 8] = ra0;
        *(uint4*)&Asm[0][row * 72 + (seg + 4) * 8] = ra1;
        *(uint4*)&Bsm[0][row * 72 + seg * 8] = rb0;
        *(uint4*)&Bsm[0][row * 72 + (seg + 4) * 8] = rb1;
    }
    __syncthreads();
    for (int m = m0; m < m1; m++) {
        int p = (m - m0) & 1;
        if (m + 1 < m1) {   // prefetch next cell into the other buffer
            int mm = m + 1;
            int craw = ((mm / 7) * 8 + (mm % 7) + 9);
            const unsigned short* Bc = Wt2 + (long)craw * 16384 + boff;
            ra0 = *(const uint4*)(Arow + mm * 64 + seg * 8);
            ra1 = *(const uint4*)(Arow + mm * 64 + (seg + 4) * 8);
            rb0 = *(const uint4*)(Bc + seg * 8);
            rb1 = *(const uint4*)(Bc + (seg + 4) * 8);
            *(uint4*)&Asm[p ^ 1][row * 72 + seg * 8] = ra0;
            *(uint4*)&Asm[p ^ 1][row * 72 + (seg + 4) * 8] = ra1;
            *(uint4*)&Bsm[p ^ 1][row * 72 + seg * 8] = rb0;
            *(uint4*)&Bsm[p ^ 1][row * 72 + (seg + 4) * 8] = rb1;
        }
        #pragma unroll
        for (int kc = 0; kc < 2; kc++) {
            bf16x8 a0 = *(bf16x8*)&Asm[p][(wrow +      mrow) * 72 + kc * 32 + q * 8];
            bf16x8 a1 = *(bf16x8*)&Asm[p][(wrow + 16 + mrow) * 72 + kc * 32 + q * 8];
            #pragma unroll
            for (int ct = 0; ct < 2; ct++) {
                bf16x8 bv = *(bf16x8*)&Bsm[p][(wcol + ct * 16 + mrow) * 72 + kc * 32 + q * 8];
                acc[0][ct] = __builtin_amdgcn_mfma_f32_16x16x32_bf16(a0, bv, acc[0][ct], 0, 0, 0);
                acc[1][ct] = __builtin_amdgcn_mfma_f32_16x16x32_bf16(a1, bv, acc[1][ct], 0, 0, 0);
            }
        }
        __syncthreads();
    }
    // C/D layout: col = lane&15, row = (lane>>4)*4 + reg. Plain stores, no RMW.
    float* ps = part + (long)s * 262144;
    #pragma unroll
    for (int rt = 0; rt < 2; rt++)
        #pragma unroll
        for (int ct = 0; ct < 2; ct++)
            #pragma unroll
            for (int r = 0; r < 4; r++) {
                int grow = row0 + wrow + rt * 16 + q * 4 + r;
                int gcol = col0 + wcol + ct * 16 + mrow;
                ps[grow * 256 + gcol] = acc[rt][ct][r];
            }
}

// ---------------- per step: gates GEMV, LSTM cell, out ---------------------
// grid 256 x 1024 threads: 4 rows/block, 8-way K-split x 2-col float2 loads.
// Per thread: 48 iters x {one 8B coalesced load, 8 FMA} (was 96 x {4B, 4}).
// Halves load-instruction count at 2x width; halves each split's serial
// chain. Weights L2-resident; read once per block.
__global__ __launch_bounds__(1024) void k_cell(const int* __restrict__ masks,
                                               const void* __restrict__ Y,
                                               const void* __restrict__ bsoc,
                                               const void* __restrict__ Wih,
                                               const void* __restrict__ bih,
                                               const void* __restrict__ Whh,
                                               const void* __restrict__ bhh,
                                               const void* __restrict__ Wout,
                                               const void* __restrict__ bout,
                                               const int* __restrict__ Tpred,
                                               const int* __restrict__ flag,
                                               float* __restrict__ h_ws,
                                               float* __restrict__ c_ws,
                                               const float* __restrict__ r_all,
                                               const float* __restrict__ part,
                                               void* __restrict__ out,
                                               int t) {
    if (t > get_tpred(Tpred)) return;
    int isf32 = flag[0];
    int tid = threadIdx.x;
    int r0 = blockIdx.x * 4;
    __shared__ __align__(16) float zT[384][4];   // z transposed: [k][local row]
    __shared__ float g2[8][4][256];              // [ksplit][row][col] partials
    // phase A: build zT = [r | e | h] for the block's 4 rows
    for (int idx = tid; idx < 1536; idx += 1024) {
        int r = idx / 384, k = idx - r * 384;
        int grow = r0 + r;
        float v;
        if (k < 64) {
            v = r_all[((long)t * 1024 + grow) * 64 + k];
        } else if (k < 320) {
            int col = k - 64;
            const float* pp = part + grow * 256 + col;
            float s0 = pp[0 * 262144] + pp[1 * 262144];
            float s1 = pp[2 * 262144] + pp[3 * 262144];
            float s2 = pp[4 * 262144] + pp[5 * 262144];
            float s3 = pp[6 * 262144] + pp[7 * 262144];
            v = fmaxf(ldin(bsoc, col, isf32) + ((s0 + s1) + (s2 + s3)), 0.f);
        } else {
            v = h_ws[grow * 64 + (k - 320)];
        }
        zT[k][r] = v;
    }
    __syncthreads();
    // phase B: 8-way K-split, 2 cols/thread, float2 (f32) / uint (bf16) loads
    int kh = tid >> 7, colg = tid & 127;
    int col = colg * 2;
    int klo = kh * 48, khi = klo + 48;
    float a00 = 0.f, a01 = 0.f, a10 = 0.f, a11 = 0.f;
    float a20 = 0.f, a21 = 0.f, a30 = 0.f, a31 = 0.f;
    if (isf32) {
        const float* W1 = (const float*)Wih;
        const float* W2 = (const float*)Whh;
        int kmid = khi < 320 ? khi : 320;
        #pragma unroll 8
        for (int k = klo; k < kmid; k++) {
            float2 wv = *(const float2*)(W1 + (long)k * 256 + col);
            f32x4 zv = *(f32x4*)&zT[k][0];
            a00 += zv[0] * wv.x; a01 += zv[0] * wv.y;
            a10 += zv[1] * wv.x; a11 += zv[1] * wv.y;
            a20 += zv[2] * wv.x; a21 += zv[2] * wv.y;
            a30 += zv[3] * wv.x; a31 += zv[3] * wv.y;
        }
        int k2 = klo > 320 ? klo : 320;
        #pragma unroll 8
        for (int k = k2; k < khi; k++) {
            float2 wv = *(const float2*)(W2 + (long)(k - 320) * 256 + col);
            f32x4 zv = *(f32x4*)&zT[k][0];
            a00 += zv[0] * wv.x; a01 += zv[0] * wv.y;
            a10 += zv[1] * wv.x; a11 += zv[1] * wv.y;
            a20 += zv[2] * wv.x; a21 += zv[2] * wv.y;
            a30 += zv[3] * wv.x; a31 += zv[3] * wv.y;
        }
    } else {
        const unsigned short* W1 = (const unsigned short*)Wih;
        const unsigned short* W2 = (const unsigned short*)Whh;
        int kmid = khi < 320 ? khi : 320;
        #pragma unroll 8
        for (int k = klo; k < kmid; k++) {
            unsigned int u = *(const unsigned int*)(W1 + (long)k * 256 + col);
            float wx = u2f((unsigned short)(u & 0xFFFF));
            float wy = u2f((unsigned short)(u >> 16));
            f32x4 zv = *(f32x4*)&zT[k][0];
            a00 += zv[0] * wx; a01 += zv[0] * wy;
            a10 += zv[1] * wx; a11 += zv[1] * wy;
            a20 += zv[2] * wx; a21 += zv[2] * wy;
            a30 += zv[3] * wx; a31 += zv[3] * wy;
        }
        int k2 = klo > 320 ? klo : 320;
        #pragma unroll 8
        for (int k = k2; k < khi; k++) {
            unsigned int u = *(const unsigned int*)(W2 + (long)(k - 320) * 256 + col);
            float wx = u2f((unsigned short)(u & 0xFFFF));
            float wy = u2f((unsigned short)(u >> 16));
            f32x4 zv = *(f32x4*)&zT[k][0];
            a00 += zv[0] * wx; a01 += zv[0] * wy;
            a10 += zv[1] * wx; a11 += zv[1] * wy;
            a20 += zv[2] * wx; a21 += zv[2] * wy;
            a30 += zv[3] * wx; a31 += zv[3] * wy;
        }
    }
    g2[kh][0][col] = a00; g2[kh][0][col + 1] = a01;
    g2[kh][1][col] = a10; g2[kh][1][col + 1] = a11;
    g2[kh][2][col] = a20; g2[kh][2][col + 1] = a21;
    g2[kh][3][col] = a30; g2[kh][3][col + 1] = a31;
    __syncthreads();
    // phase C: fold 8 K-split partials + biases (pairwise)
    if (tid < 256) {
        float bb = ldin(bih, tid, isf32) + ldin(bhh, tid, isf32);
        #pragma unroll
        for (int r = 0; r < 4; r++) {
            float s01 = g2[0][r][tid] + g2[1][r][tid];
            float s23 = g2[2][r][tid] + g2[3][r][tid];
            float s45 = g2[4][r][tid] + g2[5][r][tid];
            float s67 = g2[6][r][tid] + g2[7][r][tid];
            g2[0][r][tid] = ((s01 + s23) + (s45 + s67)) + bb;
        }
    }
    __syncthreads();
    // phase D: LSTM cell + output (4 rows x 64 lanes)
    if (tid < 256) {
        int row = tid >> 6, u = tid & 63;
        int grow = r0 + row;
        float gi = g2[0][row][u];
        float gf = g2[0][row][64 + u];
        float gg = g2[0][row][128 + u];
        float go = g2[0][row][192 + u];
        float c  = c_ws[grow * 64 + u];
        float si = 1.f / (1.f + __expf(-gi));
        float sf = 1.f / (1.f + __expf(-gf));
        float so = 1.f / (1.f + __expf(-go));
        float cn = sf * c + si * tanhf(gg);
        float hn = so * tanhf(cn);
        c_ws[grow * 64 + u] = cn;
        h_ws[grow * 64 + u] = hn;
        float p0 = hn * ldin(Wout, u * 2 + 0, isf32);
        float p1 = hn * ldin(Wout, u * 2 + 1, isf32);
        #pragma unroll
        for (int o = 32; o >= 1; o >>= 1) {
            p0 += __shfl_xor(p0, o);
            p1 += __shfl_xor(p1, o);
        }
        if (u == 0) {
            int m = masks[t * 1024 + grow];
            float o0 = 0.f, o1 = 0.f;
            if (m != 0) {
                bool appear = (t > 3) && (masks[(t - 3) * 1024 + grow] == 0);
                if (appear) {
                    o0 = ldin(Y, (t * 1024 + grow) * 2 + 0, isf32);
                    o1 = ldin(Y, (t * 1024 + grow) * 2 + 1, isf32);
                } else {
                    o0 = p0 + ldin(bout, 0, isf32);
                    o1 = p1 + ldin(bout, 1, isf32);
                }
            }
            if (!(o0 == o0)) o0 = 0.f;            // sanitize: finite diagnostics
            if (!(o1 == o1)) o1 = 0.f;
            int ofs = (t * 1024 + grow) * 2;
            if (isf32) {
                ((float*)out)[ofs + 0] = o0;
                ((float*)out)[ofs + 1] = o1;
            } else {
                ((unsigned short*)out)[ofs + 0] = f2b(o0);
                ((unsigned short*)out)[ofs + 1] = f2b(o1);
            }
        }
    }
}

extern "C" void kernel_launch(void* const* d_in, const int* in_sizes, int n_in,
                              void* d_out, int out_size, void* d_ws, size_t ws_size,
                              hipStream_t stream) {
    (void)in_sizes; (void)n_in; (void)out_size; (void)ws_size;
    const void* X     = d_in[0];
    const int*  masks = (const int*)d_in[1];
    const void* h0    = d_in[2];
    const void* c0    = d_in[3];
    const void* Y     = d_in[4];
    // d_in[5] = T_obs (unused by reference)
    const int*  Tpred = (const int*)d_in[6];
    const void* Wemb  = d_in[7];
    const void* bemb  = d_in[8];
    const void* Wsoc  = d_in[9];
    const void* bsoc  = d_in[10];
    const void* Wih   = d_in[11];
    const void* bih   = d_in[12];
    const void* Whh   = d_in[13];
    const void* bhh   = d_in[14];
    const void* Wout  = d_in[15];
    const void* bout  = d_in[16];

    char* ws = (char*)d_ws;
    float*          h_ws  = (float*)(ws + 0);
    float*          c_ws  = (float*)(ws + 262144);
    unsigned short* Wt2   = (unsigned short*)(ws + 1835008);
    unsigned short* Hbuf  = (unsigned short*)(ws + 3932160);
    int*            flag  = (int*)(ws + 11141120);
    float*          part  = (float*)(ws + 16777216);
    float*          r_all = (float*)(ws + 33554432);
    unsigned short* offs  = (unsigned short*)(ws + 41943040);
    unsigned short* ents  = (unsigned short*)(ws + 50331648);

    k_detect<<<1, 256, 0, stream>>>(Wsoc, flag);
    k_transpose<<<128, 256, 0, stream>>>(Wsoc, Wt2, flag);
    k_init<<<48, 256, 0, stream>>>(d_out, h0, c0, h_ws, c_ws, flag);
    k_codes<<<8192, 256, 0, stream>>>(X, masks, Wemb, bemb, Tpred, flag,
                                      r_all, offs, ents);
    for (int t = 0; t < 32; t++) {
        k_pool<<<1024, 256, 0, stream>>>(masks, Tpred, h_ws, offs, ents, Hbuf, t);
        k_gemm<<<512, 256, 0, stream>>>(Hbuf, Wt2, Tpred, part, t);
        k_cell<<<256, 1024, 0, stream>>>(masks, Y, bsoc, Wih, bih, Whh, bhh,
                                         Wout, bout, Tpred, flag, h_ws, c_ws,
                                         r_all, part, d_out, t);
    }
}

// Round 9
// 1075.011 us; speedup vs baseline: 1.0261x; 1.0261x over previous
//
#include <hip/hip_runtime.h>
#include <hip/hip_bf16.h>

// SocialLSTM forward, MI355X gfx950.
// Dual-dtype: float inputs may be bf16 or f32; detected at runtime from W_soc.
// ws layout (bytes):
//   h_ws  f32[1024*64]      @ 0
//   c_ws  f32[1024*64]      @ 262144
//   Wt2   bf16[64][256][64] @ 1835008   (W_soc cell-major: [cell][n][k], 2 MB)
//   Hbuf  bf16[1024*3136]   @ 3932160   (49 reachable cells * 64 hid per row)
//   flag  int32             @ 11141120  (0 = bf16 inputs, 1 = f32 inputs)
//   part  f32[8][1024*256]  @ 16777216  (K-split GEMM partials, no atomics)
//   r_all f32[32][1024][64] @ 33554432  (precomputed r = relu(coords@Wemb+b))
//   offs  u16[32*1024][64]  @ 41943040  (per (t,i): 50 prefix offsets of cell lists)
//   ents  u16[32*1024][1024]@ 50331648  (per (t,i): compacted neighbor j-lists)

typedef short bf16x8 __attribute__((ext_vector_type(8)));
typedef float f32x4 __attribute__((ext_vector_type(4)));

__device__ __forceinline__ float u2f(unsigned short u) {
    union { unsigned int i; float f; } v; v.i = ((unsigned int)u) << 16; return v.f;
}
__device__ __forceinline__ unsigned short f2b(float f) {
    __hip_bfloat16 hb = __float2bfloat16(f);
    return *(unsigned short*)&hb;
}
__device__ __forceinline__ float ldin(const void* p, int idx, int isf32) {
    return isf32 ? ((const float*)p)[idx] : u2f(((const unsigned short*)p)[idx]);
}
__device__ __forceinline__ int get_tpred(const int* p) {
    int v = p[0];
    if (v >= 0 && v <= 64) return v;
    float f = ((const float*)p)[0];
    if (f >= 0.f && f <= 64.f) return (int)f;
    float g = u2f(((const unsigned short*)p)[0]);
    if (g >= 0.f && g <= 64.f) return (int)g;
    return 31;
}

// ---------------- dtype detector: bf16-decode W_soc, look for huge/NaN -----
__global__ __launch_bounds__(256) void k_detect(const void* __restrict__ Wsoc,
                                                int* __restrict__ flag) {
    __shared__ int f;
    int tid = threadIdx.x;
    if (tid == 0) f = 0;
    __syncthreads();
    const unsigned short* p = (const unsigned short*)Wsoc;
    #pragma unroll
    for (int k = 0; k < 4; k++) {
        float v = u2f(p[tid * 4 + k]);
        if (!(v == v) || fabsf(v) > 1e20f) f = 1;   // same-address LDS write, benign
    }
    __syncthreads();
    if (tid == 0) flag[0] = f;
}

// ------- one-time: W_soc (4096x256) -> Wt2 bf16 cell-major [cell][n][k] ----
__global__ __launch_bounds__(256) void k_transpose(const void* __restrict__ Wsoc,
                                                   unsigned short* __restrict__ Wt2,
                                                   const int* __restrict__ flag) {
    __shared__ __align__(16) unsigned short tile[32 * 264];
    int isf32 = flag[0];
    int b = blockIdx.x, tid = threadIdx.x;
    int k0 = b * 32;
    if (isf32) {
        const float* W = (const float*)Wsoc;
        #pragma unroll
        for (int p = 0; p < 4; p++) {
            int kk = (tid >> 5) + p * 8;
            int n8 = (tid & 31) * 8;
            #pragma unroll
            for (int q = 0; q < 8; q++)
                tile[kk * 264 + n8 + q] = f2b(W[(k0 + kk) * 256 + n8 + q]);
        }
    } else {
        const unsigned short* W = (const unsigned short*)Wsoc;
        #pragma unroll
        for (int p = 0; p < 4; p++) {
            int kk = (tid >> 5) + p * 8;
            int n8 = (tid & 31) * 8;
            *(uint4*)&tile[kk * 264 + n8] = *(const uint4*)(W + (k0 + kk) * 256 + n8);
        }
    }
    __syncthreads();
    int n = tid;
    unsigned int packed[16];
    #pragma unroll
    for (int q = 0; q < 16; q++) {
        unsigned int lo = tile[(2 * q) * 264 + n];
        unsigned int hi = tile[(2 * q + 1) * 264 + n];
        packed[q] = lo | (hi << 16);
    }
    int craw = k0 >> 6, kk0 = k0 & 63;
    uint4* dst = (uint4*)(Wt2 + (long)craw * 16384 + (long)n * 64 + kk0);
    #pragma unroll
    for (int p = 0; p < 4; p++)
        dst[p] = make_uint4(packed[4*p], packed[4*p+1], packed[4*p+2], packed[4*p+3]);
}

// ---------------- one-time: zero d_out (dtype-sized), h0/c0 -> f32 ---------
__global__ __launch_bounds__(256) void k_init(void* __restrict__ out,
                                              const void* __restrict__ hin,
                                              const void* __restrict__ cin,
                                              float* __restrict__ h_ws,
                                              float* __restrict__ c_ws,
                                              const int* __restrict__ flag) {
    int isf32 = flag[0];
    int b = blockIdx.x, tid = threadIdx.x;
    if (b < 16) {
        uint4 z = make_uint4(0u, 0u, 0u, 0u);
        uint4* p = (uint4*)out;
        int n16 = isf32 ? 16384 : 8192;          // 65536 elems * 4 or 2 bytes / 16
        for (int idx = b * 256 + tid; idx < n16; idx += 4096) p[idx] = z;
    } else {
        int sb = b - 16;
        const void* src = (sb < 16) ? hin : cin;
        float* dst = (sb < 16) ? h_ws : c_ws;
        sb &= 15;
        int base = (sb * 256 + tid) * 16;
        #pragma unroll
        for (int p = 0; p < 16; p++) dst[base + p] = ldin(src, base + p, isf32);
    }
}

// ---------------- one-time: codes, 4 agents/block, LDS-staged coords -------
// grid 8192: t = bid>>8, agents i = (bid&255)*4 .. +3. (R7-verified.)
__global__ __launch_bounds__(256) void k_codes(const void* __restrict__ X,
                                               const int* __restrict__ masks,
                                               const void* __restrict__ Wemb,
                                               const void* __restrict__ bemb,
                                               const int* __restrict__ Tpred,
                                               const int* __restrict__ flag,
                                               float* __restrict__ r_all,
                                               unsigned short* __restrict__ offs,
                                               unsigned short* __restrict__ ents) {
    int bid = blockIdx.x;
    int t = bid >> 8, ig = bid & 255;
    if (t > get_tpred(Tpred)) return;
    int isf32 = flag[0];
    int tid = threadIdx.x;
    __shared__ float sx[1024], sy[1024];
    __shared__ unsigned char sm[1024];
    __shared__ int cnt[49];
    __shared__ unsigned short off_s[52];
    const int* mrow = masks + t * 1024;
    #pragma unroll
    for (int p = 0; p < 4; p++) {
        int j = tid + p * 256;
        sm[j] = (unsigned char)(mrow[j] != 0);
        float x, y;
        if (isf32) {
            float2 xy = *(const float2*)((const float*)X + ((long)(t * 1024 + j)) * 4 + 2);
            x = xy.x; y = xy.y;
        } else {
            unsigned int u = *(const unsigned int*)((const unsigned short*)X + ((long)(t * 1024 + j)) * 4 + 2);
            x = u2f((unsigned short)(u & 0xFFFF));
            y = u2f((unsigned short)(u >> 16));
        }
        sx[j] = x; sy[j] = y;
    }
    __syncthreads();
    {   // r = relu(coords@Wemb + bemb) for the 4 agents (thread a=tid>>6,u=tid&63)
        int a = tid >> 6, u = tid & 63;
        int i = ig * 4 + a;
        float v = ldin(Wemb, u, isf32) * sx[i] + ldin(Wemb, 64 + u, isf32) * sy[i]
                + ldin(bemb, u, isf32);
        r_all[((long)t * 1024 + i) * 64 + u] = fmaxf(v, 0.f);
    }
    for (int a = 0; a < 4; a++) {
        int i = ig * 4 + a;
        if (!sm[i]) continue;                 // block-uniform; lists unused
        if (tid < 49) cnt[tid] = 0;
        __syncthreads();
        int cc[4], rk[4];
        float cix = sx[i], ciy = sy[i];
        #pragma unroll
        for (int p = 0; p < 4; p++) {
            int j = tid + p * 256;
            cc[p] = -1;
            if (j != i && sm[j]) {
                float dx = sx[j] - cix, dy = sy[j] - ciy;
                int g0 = (int)dx, g1 = (int)dy;   // trunc toward zero == jnp.trunc
                if (g0 >= -3 && g0 <= 3 && g1 >= -3 && g1 <= 3) {
                    int c = (g0 + 3) * 7 + (g1 + 3);      // dense 0..48
                    cc[p] = c;
                    rk[p] = atomicAdd(&cnt[c], 1);
                }
            }
        }
        __syncthreads();
        if (tid == 0) {
            int o = 0;
            #pragma unroll 1
            for (int c = 0; c < 49; c++) { off_s[c] = (unsigned short)o; o += cnt[c]; }
            off_s[49] = (unsigned short)o;
        }
        __syncthreads();
        unsigned short* eb = ents + ((long)t * 1024 + i) * 1024;
        #pragma unroll
        for (int p = 0; p < 4; p++)
            if (cc[p] >= 0)
                eb[off_s[cc[p]] + rk[p]] = (unsigned short)(tid + p * 256);
        if (tid < 50) offs[((long)t * 1024 + i) * 64 + tid] = off_s[tid];
    }
}

// ---------------- per step: pure gather-accumulate pooling -> Hbuf ---------
// 1024 blocks (one per agent) keeps ~16 waves/CU of independent gather work
// in flight — this phase is latency-bound, parallelism is the currency.
// (R4-verified fastest variant.)
__global__ __launch_bounds__(256) void k_pool(const int* __restrict__ masks,
                                              const int* __restrict__ Tpred,
                                              const float* __restrict__ h_ws,
                                              const unsigned short* __restrict__ offs,
                                              const unsigned short* __restrict__ ents,
                                              unsigned short* __restrict__ Hbuf,
                                              int t) {
    if (t > get_tpred(Tpred)) return;
    int i = blockIdx.x, tid = threadIdx.x;
    long hb_base = (long)i * 3136;
    if (masks[t * 1024 + i] == 0) {   // block-uniform: H row is all zeros
        unsigned int* hp = (unsigned int*)(Hbuf + hb_base);
        for (int idx = tid; idx < 1568; idx += 256) hp[idx] = 0u;
        return;
    }
    __shared__ __align__(16) unsigned short el[1024];
    __shared__ unsigned short of[52];
    if (tid < 50) of[tid] = offs[((long)t * 1024 + i) * 64 + tid];
    {
        const uint4* src = (const uint4*)(ents + ((long)t * 1024 + i) * 1024);
        uint4* dst = (uint4*)el;
        if (tid < 128) dst[tid] = src[tid];   // stage full list; tail garbage unread
    }
    __syncthreads();
    int w = tid >> 6, lane = tid & 63;
    for (int c = w; c < 49; c += 4) {       // round-robin cells over 4 waves
        int k = of[c], n = of[c + 1];
        float acc = 0.f;
        for (; k + 8 <= n; k += 8) {        // 8 loads in flight per group
            int j0 = el[k], j1 = el[k + 1], j2 = el[k + 2], j3 = el[k + 3];
            int j4 = el[k + 4], j5 = el[k + 5], j6 = el[k + 6], j7 = el[k + 7];
            float v0 = h_ws[j0 * 64 + lane];
            float v1 = h_ws[j1 * 64 + lane];
            float v2 = h_ws[j2 * 64 + lane];
            float v3 = h_ws[j3 * 64 + lane];
            float v4 = h_ws[j4 * 64 + lane];
            float v5 = h_ws[j5 * 64 + lane];
            float v6 = h_ws[j6 * 64 + lane];
            float v7 = h_ws[j7 * 64 + lane];
            acc += ((v0 + v1) + (v2 + v3)) + ((v4 + v5) + (v6 + v7));
        }
        for (; k < n; k++) acc += h_ws[el[k] * 64 + lane];
        Hbuf[hb_base + c * 64 + lane] = f2b(acc);
    }
}

// ---------------- per step: part[s] = H @ W_soc slice (MFMA, dbuf LDS) -----
// grid 512: ch = bid&3 (64-col slice), s = (bid>>2)&7 (K-split), rb = bid>>5.
// B-tile staged from cell-major Wt2: fully contiguous per cell. (R4-verified.)
__global__ __launch_bounds__(256) void k_gemm(const unsigned short* __restrict__ Hbuf,
                                              const unsigned short* __restrict__ Wt2,
                                              const int* __restrict__ Tpred,
                                              float* __restrict__ part,
                                              int t) {
    if (t > get_tpred(Tpred)) return;
    int bid = blockIdx.x, tid = threadIdx.x;
    int ch = bid & 3, s = (bid >> 2) & 7, rb = bid >> 5;
    int row0 = rb * 64, col0 = ch * 64;
    int m0 = (49 * s) >> 3, m1 = (49 * (s + 1)) >> 3;   // 6,6,6,6,6,6,6,7 cells
    __shared__ __align__(16) short Asm[2][64 * 72];   // double-buffered
    __shared__ __align__(16) short Bsm[2][64 * 72];
    int w = tid >> 6, lane = tid & 63;
    int wrow = (w & 1) * 32, wcol = (w >> 1) * 32;
    int mrow = lane & 15, q = lane >> 4;
    int row = tid >> 2, seg = tid & 3;
    const unsigned short* Arow = Hbuf + (long)(row0 + row) * 3136;
    const long boff = (long)(col0 + row) * 64;
    f32x4 acc[2][2];
    f32x4 zz = {0.f, 0.f, 0.f, 0.f};
    #pragma unroll
    for (int a = 0; a < 2; a++)
        #pragma unroll
        for (int b = 0; b < 2; b++) acc[a][b] = zz;
    uint4 ra0, ra1, rb0, rb1;
    {   // prologue: load cell m0
        int craw = ((m0 / 7) * 8 + (m0 % 7) + 9);
        const unsigned short* Bc = Wt2 + (long)craw * 16384 + boff;
        ra0 = *(const uint4*)(Arow + m0 * 64 + seg * 8);
        ra1 = *(const uint4*)(Arow + m0 * 64 + (seg + 4) * 8);
        rb0 = *(const uint4*)(Bc + seg * 8);
        rb1 = *(const uint4*)(Bc + (seg + 4) * 8);
        *(uint4*)&Asm[0][row * 72 + seg * 8] = ra0;
        *(uint4*)&Asm[0][row * 72 + (seg + 4) * 8] = ra1;
        *(uint4*)&Bsm[0][row * 72 + seg * 8] = rb0;
        *(uint4*)&Bsm[0][row * 72 + (seg + 4) * 8] = rb1;
    }
    __syncthreads();
    for (int m = m0; m < m1; m++) {
        int p = (m - m0) & 1;
        if (m + 1 < m1) {   // prefetch next cell into the other buffer
            int mm = m + 1;
            int craw = ((mm / 7) * 8 + (mm % 7) + 9);
            const unsigned short* Bc = Wt2 + (long)craw * 16384 + boff;
            ra0 = *(const uint4*)(Arow + mm * 64 + seg * 8);
            ra1 = *(const uint4*)(Arow + mm * 64 + (seg + 4) * 8);
            rb0 = *(const uint4*)(Bc + seg * 8);
            rb1 = *(const uint4*)(Bc + (seg + 4) * 8);
            *(uint4*)&Asm[p ^ 1][row * 72 + seg * 8] = ra0;
            *(uint4*)&Asm[p ^ 1][row * 72 + (seg + 4) * 8] = ra1;
            *(uint4*)&Bsm[p ^ 1][row * 72 + seg * 8] = rb0;
            *(uint4*)&Bsm[p ^ 1][row * 72 + (seg + 4) * 8] = rb1;
        }
        #pragma unroll
        for (int kc = 0; kc < 2; kc++) {
            bf16x8 a0 = *(bf16x8*)&Asm[p][(wrow +      mrow) * 72 + kc * 32 + q * 8];
            bf16x8 a1 = *(bf16x8*)&Asm[p][(wrow + 16 + mrow) * 72 + kc * 32 + q * 8];
            #pragma unroll
            for (int ct = 0; ct < 2; ct++) {
                bf16x8 bv = *(bf16x8*)&Bsm[p][(wcol + ct * 16 + mrow) * 72 + kc * 32 + q * 8];
                acc[0][ct] = __builtin_amdgcn_mfma_f32_16x16x32_bf16(a0, bv, acc[0][ct], 0, 0, 0);
                acc[1][ct] = __builtin_amdgcn_mfma_f32_16x16x32_bf16(a1, bv, acc[1][ct], 0, 0, 0);
            }
        }
        __syncthreads();
    }
    // C/D layout: col = lane&15, row = (lane>>4)*4 + reg. Plain stores, no RMW.
    float* ps = part + (long)s * 262144;
    #pragma unroll
    for (int rt = 0; rt < 2; rt++)
        #pragma unroll
        for (int ct = 0; ct < 2; ct++)
            #pragma unroll
            for (int r = 0; r < 4; r++) {
                int grow = row0 + wrow + rt * 16 + q * 4 + r;
                int gcol = col0 + wcol + ct * 16 + mrow;
                ps[grow * 256 + gcol] = acc[rt][ct][r];
            }
}

// ---------------- per step: gates GEMV, LSTM cell, out ---------------------
// grid 256 x 1024 threads: 4 rows/block, 4-way K-split (96 k-iters each).
// 16 waves/CU + unroll-8 load pipelining. (R4/R7-verified fastest variant;
// R8's 8-way float2 variant regressed — fewer independent chains + 38KB LDS.)
__global__ __launch_bounds__(1024) void k_cell(const int* __restrict__ masks,
                                               const void* __restrict__ Y,
                                               const void* __restrict__ bsoc,
                                               const void* __restrict__ Wih,
                                               const void* __restrict__ bih,
                                               const void* __restrict__ Whh,
                                               const void* __restrict__ bhh,
                                               const void* __restrict__ Wout,
                                               const void* __restrict__ bout,
                                               const int* __restrict__ Tpred,
                                               const int* __restrict__ flag,
                                               float* __restrict__ h_ws,
                                               float* __restrict__ c_ws,
                                               const float* __restrict__ r_all,
                                               const float* __restrict__ part,
                                               void* __restrict__ out,
                                               int t) {
    if (t > get_tpred(Tpred)) return;
    int isf32 = flag[0];
    int tid = threadIdx.x;
    int r0 = blockIdx.x * 4;
    __shared__ __align__(16) float zT[384][4];   // z transposed: [k][local row]
    __shared__ float g2[4][4][256];              // [ksplit][row][col] partials
    // phase A: build zT = [r | e | h] for the block's 4 rows
    for (int idx = tid; idx < 1536; idx += 1024) {
        int r = idx / 384, k = idx - r * 384;
        int grow = r0 + r;
        float v;
        if (k < 64) {
            v = r_all[((long)t * 1024 + grow) * 64 + k];
        } else if (k < 320) {
            int col = k - 64;
            const float* pp = part + grow * 256 + col;
            float s0 = pp[0 * 262144] + pp[1 * 262144];
            float s1 = pp[2 * 262144] + pp[3 * 262144];
            float s2 = pp[4 * 262144] + pp[5 * 262144];
            float s3 = pp[6 * 262144] + pp[7 * 262144];
            v = fmaxf(ldin(bsoc, col, isf32) + ((s0 + s1) + (s2 + s3)), 0.f);
        } else {
            v = h_ws[grow * 64 + (k - 320)];
        }
        zT[k][r] = v;
    }
    __syncthreads();
    // phase B: partial gates; dtype branch hoisted, unroll-8 load pipelining
    int kh = tid >> 8, col = tid & 255;
    int klo = kh * 96, khi = klo + 96;
    float a0 = 0.f, a1 = 0.f, a2 = 0.f, a3 = 0.f;
    if (isf32) {
        const float* W1 = (const float*)Wih;
        const float* W2 = (const float*)Whh;
        int kmid = khi < 320 ? khi : 320;
        #pragma unroll 8
        for (int k = klo; k < kmid; k++) {
            float wv = W1[(long)k * 256 + col];
            f32x4 zv = *(f32x4*)&zT[k][0];
            a0 += zv[0] * wv; a1 += zv[1] * wv; a2 += zv[2] * wv; a3 += zv[3] * wv;
        }
        int k2 = klo > 320 ? klo : 320;
        #pragma unroll 8
        for (int k = k2; k < khi; k++) {
            float wv = W2[(long)(k - 320) * 256 + col];
            f32x4 zv = *(f32x4*)&zT[k][0];
            a0 += zv[0] * wv; a1 += zv[1] * wv; a2 += zv[2] * wv; a3 += zv[3] * wv;
        }
    } else {
        const unsigned short* W1 = (const unsigned short*)Wih;
        const unsigned short* W2 = (const unsigned short*)Whh;
        int kmid = khi < 320 ? khi : 320;
        #pragma unroll 8
        for (int k = klo; k < kmid; k++) {
            float wv = u2f(W1[(long)k * 256 + col]);
            f32x4 zv = *(f32x4*)&zT[k][0];
            a0 += zv[0] * wv; a1 += zv[1] * wv; a2 += zv[2] * wv; a3 += zv[3] * wv;
        }
        int k2 = klo > 320 ? klo : 320;
        #pragma unroll 8
        for (int k = k2; k < khi; k++) {
            float wv = u2f(W2[(long)(k - 320) * 256 + col]);
            f32x4 zv = *(f32x4*)&zT[k][0];
            a0 += zv[0] * wv; a1 += zv[1] * wv; a2 += zv[2] * wv; a3 += zv[3] * wv;
        }
    }
    g2[kh][0][col] = a0; g2[kh][1][col] = a1;
    g2[kh][2][col] = a2; g2[kh][3][col] = a3;
    __syncthreads();
    // phase C: fold 4 K-split partials + biases
    if (tid < 256) {
        float bb = ldin(bih, tid, isf32) + ldin(bhh, tid, isf32);
        #pragma unroll
        for (int r = 0; r < 4; r++)
            g2[0][r][tid] = ((g2[0][r][tid] + g2[1][r][tid])
                           + (g2[2][r][tid] + g2[3][r][tid])) + bb;
    }
    __syncthreads();
    // phase D: LSTM cell + output (4 rows x 64 lanes)
    if (tid < 256) {
        int row = tid >> 6, u = tid & 63;
        int grow = r0 + row;
        float gi = g2[0][row][u];
        float gf = g2[0][row][64 + u];
        float gg = g2[0][row][128 + u];
        float go = g2[0][row][192 + u];
        float c  = c_ws[grow * 64 + u];
        float si = 1.f / (1.f + __expf(-gi));
        float sf = 1.f / (1.f + __expf(-gf));
        float so = 1.f / (1.f + __expf(-go));
        float cn = sf * c + si * tanhf(gg);
        float hn = so * tanhf(cn);
        c_ws[grow * 64 + u] = cn;
        h_ws[grow * 64 + u] = hn;
        float p0 = hn * ldin(Wout, u * 2 + 0, isf32);
        float p1 = hn * ldin(Wout, u * 2 + 1, isf32);
        #pragma unroll
        for (int o = 32; o >= 1; o >>= 1) {
            p0 += __shfl_xor(p0, o);
            p1 += __shfl_xor(p1, o);
        }
        if (u == 0) {
            int m = masks[t * 1024 + grow];
            float o0 = 0.f, o1 = 0.f;
            if (m != 0) {
                bool appear = (t > 3) && (masks[(t - 3) * 1024 + grow] == 0);
                if (appear) {
                    o0 = ldin(Y, (t * 1024 + grow) * 2 + 0, isf32);
                    o1 = ldin(Y, (t * 1024 + grow) * 2 + 1, isf32);
                } else {
                    o0 = p0 + ldin(bout, 0, isf32);
                    o1 = p1 + ldin(bout, 1, isf32);
                }
            }
            if (!(o0 == o0)) o0 = 0.f;            // sanitize: finite diagnostics
            if (!(o1 == o1)) o1 = 0.f;
            int ofs = (t * 1024 + grow) * 2;
            if (isf32) {
                ((float*)out)[ofs + 0] = o0;
                ((float*)out)[ofs + 1] = o1;
            } else {
                ((unsigned short*)out)[ofs + 0] = f2b(o0);
                ((unsigned short*)out)[ofs + 1] = f2b(o1);
            }
        }
    }
}

extern "C" void kernel_launch(void* const* d_in, const int* in_sizes, int n_in,
                              void* d_out, int out_size, void* d_ws, size_t ws_size,
                              hipStream_t stream) {
    (void)in_sizes; (void)n_in; (void)out_size; (void)ws_size;
    const void* X     = d_in[0];
    const int*  masks = (const int*)d_in[1];
    const void* h0    = d_in[2];
    const void* c0    = d_in[3];
    const void* Y     = d_in[4];
    // d_in[5] = T_obs (unused by reference)
    const int*  Tpred = (const int*)d_in[6];
    const void* Wemb  = d_in[7];
    const void* bemb  = d_in[8];
    const void* Wsoc  = d_in[9];
    const void* bsoc  = d_in[10];
    const void* Wih   = d_in[11];
    const void* bih   = d_in[12];
    const void* Whh   = d_in[13];
    const void* bhh   = d_in[14];
    const void* Wout  = d_in[15];
    const void* bout  = d_in[16];

    char* ws = (char*)d_ws;
    float*          h_ws  = (float*)(ws + 0);
    float*          c_ws  = (float*)(ws + 262144);
    unsigned short* Wt2   = (unsigned short*)(ws + 1835008);
    unsigned short* Hbuf  = (unsigned short*)(ws + 3932160);
    int*            flag  = (int*)(ws + 11141120);
    float*          part  = (float*)(ws + 16777216);
    float*          r_all = (float*)(ws + 33554432);
    unsigned short* offs  = (unsigned short*)(ws + 41943040);
    unsigned short* ents  = (unsigned short*)(ws + 50331648);

    k_detect<<<1, 256, 0, stream>>>(Wsoc, flag);
    k_transpose<<<128, 256, 0, stream>>>(Wsoc, Wt2, flag);
    k_init<<<48, 256, 0, stream>>>(d_out, h0, c0, h_ws, c_ws, flag);
    k_codes<<<8192, 256, 0, stream>>>(X, masks, Wemb, bemb, Tpred, flag,
                                      r_all, offs, ents);
    for (int t = 0; t < 32; t++) {
        k_pool<<<1024, 256, 0, stream>>>(masks, Tpred, h_ws, offs, ents, Hbuf, t);
        k_gemm<<<512, 256, 0, stream>>>(Hbuf, Wt2, Tpred, part, t);
        k_cell<<<256, 1024, 0, stream>>>(masks, Y, bsoc, Wih, bih, Whh, bhh,
                                         Wout, bout, Tpred, flag, h_ws, c_ws,
                                         r_all, part, d_out, t);
    }
}

// Round 10
// 1067.006 us; speedup vs baseline: 1.0338x; 1.0075x over previous
//
#include <hip/hip_runtime.h>
#include <hip/hip_bf16.h>

// SocialLSTM forward, MI355X gfx950.
// Dual-dtype: float inputs may be bf16 or f32; detected at runtime from W_soc.
// ws layout (bytes):
//   h_ws  f32[1024*64]      @ 0
//   c_ws  f32[1024*64]      @ 262144
//   Wt2   bf16[64][256][64] @ 1835008   (W_soc cell-major: [cell][n][k], 2 MB)
//   Hbuf  bf16[1024*3136]   @ 3932160   (49 reachable cells * 64 hid per row)
//   flag  int32             @ 11141120  (0 = bf16 inputs, 1 = f32 inputs)
//   part  f32[8][1024*256]  @ 16777216  (K-split GEMM partials, no atomics)
//   r_all f32[32][1024][64] @ 33554432  (precomputed r = relu(coords@Wemb+b))
//   offs  u16[32*1024][64]  @ 41943040  (per (t,i): 50 prefix offsets of cell lists)
//   ents  u16[32*1024][1024]@ 50331648  (per (t,i): compacted neighbor j-lists)

typedef short bf16x8 __attribute__((ext_vector_type(8)));
typedef float f32x4 __attribute__((ext_vector_type(4)));

__device__ __forceinline__ float u2f(unsigned short u) {
    union { unsigned int i; float f; } v; v.i = ((unsigned int)u) << 16; return v.f;
}
__device__ __forceinline__ unsigned short f2b(float f) {
    __hip_bfloat16 hb = __float2bfloat16(f);
    return *(unsigned short*)&hb;
}
__device__ __forceinline__ float ldin(const void* p, int idx, int isf32) {
    return isf32 ? ((const float*)p)[idx] : u2f(((const unsigned short*)p)[idx]);
}
__device__ __forceinline__ int get_tpred(const int* p) {
    int v = p[0];
    if (v >= 0 && v <= 64) return v;
    float f = ((const float*)p)[0];
    if (f >= 0.f && f <= 64.f) return (int)f;
    float g = u2f(((const unsigned short*)p)[0]);
    if (g >= 0.f && g <= 64.f) return (int)g;
    return 31;
}

// ---------------- dtype detector: bf16-decode W_soc, look for huge/NaN -----
__global__ __launch_bounds__(256) void k_detect(const void* __restrict__ Wsoc,
                                                int* __restrict__ flag) {
    __shared__ int f;
    int tid = threadIdx.x;
    if (tid == 0) f = 0;
    __syncthreads();
    const unsigned short* p = (const unsigned short*)Wsoc;
    #pragma unroll
    for (int k = 0; k < 4; k++) {
        float v = u2f(p[tid * 4 + k]);
        if (!(v == v) || fabsf(v) > 1e20f) f = 1;   // same-address LDS write, benign
    }
    __syncthreads();
    if (tid == 0) flag[0] = f;
}

// ------- one-time: W_soc (4096x256) -> Wt2 bf16 cell-major [cell][n][k] ----
__global__ __launch_bounds__(256) void k_transpose(const void* __restrict__ Wsoc,
                                                   unsigned short* __restrict__ Wt2,
                                                   const int* __restrict__ flag) {
    __shared__ __align__(16) unsigned short tile[32 * 264];
    int isf32 = flag[0];
    int b = blockIdx.x, tid = threadIdx.x;
    int k0 = b * 32;
    if (isf32) {
        const float* W = (const float*)Wsoc;
        #pragma unroll
        for (int p = 0; p < 4; p++) {
            int kk = (tid >> 5) + p * 8;
            int n8 = (tid & 31) * 8;
            #pragma unroll
            for (int q = 0; q < 8; q++)
                tile[kk * 264 + n8 + q] = f2b(W[(k0 + kk) * 256 + n8 + q]);
        }
    } else {
        const unsigned short* W = (const unsigned short*)Wsoc;
        #pragma unroll
        for (int p = 0; p < 4; p++) {
            int kk = (tid >> 5) + p * 8;
            int n8 = (tid & 31) * 8;
            *(uint4*)&tile[kk * 264 + n8] = *(const uint4*)(W + (k0 + kk) * 256 + n8);
        }
    }
    __syncthreads();
    int n = tid;
    unsigned int packed[16];
    #pragma unroll
    for (int q = 0; q < 16; q++) {
        unsigned int lo = tile[(2 * q) * 264 + n];
        unsigned int hi = tile[(2 * q + 1) * 264 + n];
        packed[q] = lo | (hi << 16);
    }
    int craw = k0 >> 6, kk0 = k0 & 63;
    uint4* dst = (uint4*)(Wt2 + (long)craw * 16384 + (long)n * 64 + kk0);
    #pragma unroll
    for (int p = 0; p < 4; p++)
        dst[p] = make_uint4(packed[4*p], packed[4*p+1], packed[4*p+2], packed[4*p+3]);
}

// ---------------- one-time: zero d_out (dtype-sized), h0/c0 -> f32 ---------
__global__ __launch_bounds__(256) void k_init(void* __restrict__ out,
                                              const void* __restrict__ hin,
                                              const void* __restrict__ cin,
                                              float* __restrict__ h_ws,
                                              float* __restrict__ c_ws,
                                              const int* __restrict__ flag) {
    int isf32 = flag[0];
    int b = blockIdx.x, tid = threadIdx.x;
    if (b < 16) {
        uint4 z = make_uint4(0u, 0u, 0u, 0u);
        uint4* p = (uint4*)out;
        int n16 = isf32 ? 16384 : 8192;          // 65536 elems * 4 or 2 bytes / 16
        for (int idx = b * 256 + tid; idx < n16; idx += 4096) p[idx] = z;
    } else {
        int sb = b - 16;
        const void* src = (sb < 16) ? hin : cin;
        float* dst = (sb < 16) ? h_ws : c_ws;
        sb &= 15;
        int base = (sb * 256 + tid) * 16;
        #pragma unroll
        for (int p = 0; p < 16; p++) dst[base + p] = ldin(src, base + p, isf32);
    }
}

// ---------------- one-time: codes, 4 agents/block, LDS-staged coords -------
// grid 8192: t = bid>>8, agents i = (bid&255)*4 .. +3. (R7/R9-verified.)
// Serial tid==0 prefix loop replaced by a wave-0 shuffle scan (6 shfl_up
// steps, ~50cy vs ~1000cy of dependent LDS scalar ops on the critical path).
__global__ __launch_bounds__(256) void k_codes(const void* __restrict__ X,
                                               const int* __restrict__ masks,
                                               const void* __restrict__ Wemb,
                                               const void* __restrict__ bemb,
                                               const int* __restrict__ Tpred,
                                               const int* __restrict__ flag,
                                               float* __restrict__ r_all,
                                               unsigned short* __restrict__ offs,
                                               unsigned short* __restrict__ ents) {
    int bid = blockIdx.x;
    int t = bid >> 8, ig = bid & 255;
    if (t > get_tpred(Tpred)) return;
    int isf32 = flag[0];
    int tid = threadIdx.x;
    __shared__ float sx[1024], sy[1024];
    __shared__ unsigned char sm[1024];
    __shared__ int cnt[49];
    __shared__ unsigned short off_s[52];
    const int* mrow = masks + t * 1024;
    #pragma unroll
    for (int p = 0; p < 4; p++) {
        int j = tid + p * 256;
        sm[j] = (unsigned char)(mrow[j] != 0);
        float x, y;
        if (isf32) {
            float2 xy = *(const float2*)((const float*)X + ((long)(t * 1024 + j)) * 4 + 2);
            x = xy.x; y = xy.y;
        } else {
            unsigned int u = *(const unsigned int*)((const unsigned short*)X + ((long)(t * 1024 + j)) * 4 + 2);
            x = u2f((unsigned short)(u & 0xFFFF));
            y = u2f((unsigned short)(u >> 16));
        }
        sx[j] = x; sy[j] = y;
    }
    __syncthreads();
    {   // r = relu(coords@Wemb + bemb) for the 4 agents (thread a=tid>>6,u=tid&63)
        int a = tid >> 6, u = tid & 63;
        int i = ig * 4 + a;
        float v = ldin(Wemb, u, isf32) * sx[i] + ldin(Wemb, 64 + u, isf32) * sy[i]
                + ldin(bemb, u, isf32);
        r_all[((long)t * 1024 + i) * 64 + u] = fmaxf(v, 0.f);
    }
    for (int a = 0; a < 4; a++) {
        int i = ig * 4 + a;
        if (!sm[i]) continue;                 // block-uniform; lists unused
        if (tid < 49) cnt[tid] = 0;
        __syncthreads();
        int cc[4], rk[4];
        float cix = sx[i], ciy = sy[i];
        #pragma unroll
        for (int p = 0; p < 4; p++) {
            int j = tid + p * 256;
            cc[p] = -1;
            if (j != i && sm[j]) {
                float dx = sx[j] - cix, dy = sy[j] - ciy;
                int g0 = (int)dx, g1 = (int)dy;   // trunc toward zero == jnp.trunc
                if (g0 >= -3 && g0 <= 3 && g1 >= -3 && g1 <= 3) {
                    int c = (g0 + 3) * 7 + (g1 + 3);      // dense 0..48
                    cc[p] = c;
                    rk[p] = atomicAdd(&cnt[c], 1);
                }
            }
        }
        __syncthreads();
        if (tid < 64) {   // wave-0 inclusive shuffle scan over 49 counts
            int v = (tid < 49) ? cnt[tid] : 0;
            int x = v;
            #pragma unroll
            for (int o = 1; o < 64; o <<= 1) {
                int y = __shfl_up(x, o);
                if ((tid & 63) >= o) x += y;
            }
            if (tid < 49) off_s[tid] = (unsigned short)(x - v);   // exclusive
            if (tid == 48) off_s[49] = (unsigned short)x;         // total
        }
        __syncthreads();
        unsigned short* eb = ents + ((long)t * 1024 + i) * 1024;
        #pragma unroll
        for (int p = 0; p < 4; p++)
            if (cc[p] >= 0)
                eb[off_s[cc[p]] + rk[p]] = (unsigned short)(tid + p * 256);
        if (tid < 50) offs[((long)t * 1024 + i) * 64 + tid] = off_s[tid];
    }
}

// ---------------- per step: pure gather-accumulate pooling -> Hbuf ---------
// 1024 blocks (one per agent) keeps ~16 waves/CU of independent gather work
// in flight — this phase is latency-bound, parallelism is the currency.
// (R4-verified fastest variant.)
__global__ __launch_bounds__(256) void k_pool(const int* __restrict__ masks,
                                              const int* __restrict__ Tpred,
                                              const float* __restrict__ h_ws,
                                              const unsigned short* __restrict__ offs,
                                              const unsigned short* __restrict__ ents,
                                              unsigned short* __restrict__ Hbuf,
                                              int t) {
    if (t > get_tpred(Tpred)) return;
    int i = blockIdx.x, tid = threadIdx.x;
    long hb_base = (long)i * 3136;
    if (masks[t * 1024 + i] == 0) {   // block-uniform: H row is all zeros
        unsigned int* hp = (unsigned int*)(Hbuf + hb_base);
        for (int idx = tid; idx < 1568; idx += 256) hp[idx] = 0u;
        return;
    }
    __shared__ __align__(16) unsigned short el[1024];
    __shared__ unsigned short of[52];
    if (tid < 50) of[tid] = offs[((long)t * 1024 + i) * 64 + tid];
    {
        const uint4* src = (const uint4*)(ents + ((long)t * 1024 + i) * 1024);
        uint4* dst = (uint4*)el;
        if (tid < 128) dst[tid] = src[tid];   // stage full list; tail garbage unread
    }
    __syncthreads();
    int w = tid >> 6, lane = tid & 63;
    for (int c = w; c < 49; c += 4) {       // round-robin cells over 4 waves
        int k = of[c], n = of[c + 1];
        float acc = 0.f;
        for (; k + 8 <= n; k += 8) {        // 8 loads in flight per group
            int j0 = el[k], j1 = el[k + 1], j2 = el[k + 2], j3 = el[k + 3];
            int j4 = el[k + 4], j5 = el[k + 5], j6 = el[k + 6], j7 = el[k + 7];
            float v0 = h_ws[j0 * 64 + lane];
            float v1 = h_ws[j1 * 64 + lane];
            float v2 = h_ws[j2 * 64 + lane];
            float v3 = h_ws[j3 * 64 + lane];
            float v4 = h_ws[j4 * 64 + lane];
            float v5 = h_ws[j5 * 64 + lane];
            float v6 = h_ws[j6 * 64 + lane];
            float v7 = h_ws[j7 * 64 + lane];
            acc += ((v0 + v1) + (v2 + v3)) + ((v4 + v5) + (v6 + v7));
        }
        for (; k < n; k++) acc += h_ws[el[k] * 64 + lane];
        Hbuf[hb_base + c * 64 + lane] = f2b(acc);
    }
}

// ---------------- per step: part[s] = H @ W_soc slice (MFMA, dbuf LDS) -----
// grid 512: ch = bid&3 (64-col slice), s = (bid>>2)&7 (K-split), rb = bid>>5.
// B-tile staged from cell-major Wt2: fully contiguous per cell. (R4-verified.)
__global__ __launch_bounds__(256) void k_gemm(const unsigned short* __restrict__ Hbuf,
                                              const unsigned short* __restrict__ Wt2,
                                              const int* __restrict__ Tpred,
                                              float* __restrict__ part,
                                              int t) {
    if (t > get_tpred(Tpred)) return;
    int bid = blockIdx.x, tid = threadIdx.x;
    int ch = bid & 3, s = (bid >> 2) & 7, rb = bid >> 5;
    int row0 = rb * 64, col0 = ch * 64;
    int m0 = (49 * s) >> 3, m1 = (49 * (s + 1)) >> 3;   // 6,6,6,6,6,6,6,7 cells
    __shared__ __align__(16) short Asm[2][64 * 72];   // double-buffered
    __shared__ __align__(16) short Bsm[2][64 * 72];
    int w = tid >> 6, lane = tid & 63;
    int wrow = (w & 1) * 32, wcol = (w >> 1) * 32;
    int mrow = lane & 15, q = lane >> 4;
    int row = tid >> 2, seg = tid & 3;
    const unsigned short* Arow = Hbuf + (long)(row0 + row) * 3136;
    const long boff = (long)(col0 + row) * 64;
    f32x4 acc[2][2];
    f32x4 zz = {0.f, 0.f, 0.f, 0.f};
    #pragma unroll
    for (int a = 0; a < 2; a++)
        #pragma unroll
        for (int b = 0; b < 2; b++) acc[a][b] = zz;
    uint4 ra0, ra1, rb0, rb1;
    {   // prologue: load cell m0
        int craw = ((m0 / 7) * 8 + (m0 % 7) + 9);
        const unsigned short* Bc = Wt2 + (long)craw * 16384 + boff;
        ra0 = *(const uint4*)(Arow + m0 * 64 + seg * 8);
        ra1 = *(const uint4*)(Arow + m0 * 64 + (seg + 4) * 8);
        rb0 = *(const uint4*)(Bc + seg * 8);
        rb1 = *(const uint4*)(Bc + (seg + 4) * 8);
        *(uint4*)&Asm[0][row * 72 + seg * 8] = ra0;
        *(uint4*)&Asm[0][row * 72 + (seg + 4) * 8] = ra1;
        *(uint4*)&Bsm[0][row * 72 + seg * 8] = rb0;
        *(uint4*)&Bsm[0][row * 72 + (seg + 4) * 8] = rb1;
    }
    __syncthreads();
    for (int m = m0; m < m1; m++) {
        int p = (m - m0) & 1;
        if (m + 1 < m1) {   // prefetch next cell into the other buffer
            int mm = m + 1;
            int craw = ((mm / 7) * 8 + (mm % 7) + 9);
            const unsigned short* Bc = Wt2 + (long)craw * 16384 + boff;
            ra0 = *(const uint4*)(Arow + mm * 64 + seg * 8);
            ra1 = *(const uint4*)(Arow + mm * 64 + (seg + 4) * 8);
            rb0 = *(const uint4*)(Bc + seg * 8);
            rb1 = *(const uint4*)(Bc + (seg + 4) * 8);
            *(uint4*)&Asm[p ^ 1][row * 72 + seg * 8] = ra0;
            *(uint4*)&Asm[p ^ 1][row * 72 + (seg + 4) * 8] = ra1;
            *(uint4*)&Bsm[p ^ 1][row * 72 + seg * 8] = rb0;
            *(uint4*)&Bsm[p ^ 1][row * 72 + (seg + 4) * 8] = rb1;
        }
        #pragma unroll
        for (int kc = 0; kc < 2; kc++) {
            bf16x8 a0 = *(bf16x8*)&Asm[p][(wrow +      mrow) * 72 + kc * 32 + q * 8];
            bf16x8 a1 = *(bf16x8*)&Asm[p][(wrow + 16 + mrow) * 72 + kc * 32 + q * 8];
            #pragma unroll
            for (int ct = 0; ct < 2; ct++) {
                bf16x8 bv = *(bf16x8*)&Bsm[p][(wcol + ct * 16 + mrow) * 72 + kc * 32 + q * 8];
                acc[0][ct] = __builtin_amdgcn_mfma_f32_16x16x32_bf16(a0, bv, acc[0][ct], 0, 0, 0);
                acc[1][ct] = __builtin_amdgcn_mfma_f32_16x16x32_bf16(a1, bv, acc[1][ct], 0, 0, 0);
            }
        }
        __syncthreads();
    }
    // C/D layout: col = lane&15, row = (lane>>4)*4 + reg. Plain stores, no RMW.
    float* ps = part + (long)s * 262144;
    #pragma unroll
    for (int rt = 0; rt < 2; rt++)
        #pragma unroll
        for (int ct = 0; ct < 2; ct++)
            #pragma unroll
            for (int r = 0; r < 4; r++) {
                int grow = row0 + wrow + rt * 16 + q * 4 + r;
                int gcol = col0 + wcol + ct * 16 + mrow;
                ps[grow * 256 + gcol] = acc[rt][ct][r];
            }
}

// ---------------- per step: gates GEMV, LSTM cell, out ---------------------
// grid 256 x 1024 threads: 4 rows/block, 4-way K-split (96 k-iters each).
// 16 waves/CU + unroll-8 load pipelining. (R4/R7/R9-verified fastest variant.)
__global__ __launch_bounds__(1024) void k_cell(const int* __restrict__ masks,
                                               const void* __restrict__ Y,
                                               const void* __restrict__ bsoc,
                                               const void* __restrict__ Wih,
                                               const void* __restrict__ bih,
                                               const void* __restrict__ Whh,
                                               const void* __restrict__ bhh,
                                               const void* __restrict__ Wout,
                                               const void* __restrict__ bout,
                                               const int* __restrict__ Tpred,
                                               const int* __restrict__ flag,
                                               float* __restrict__ h_ws,
                                               float* __restrict__ c_ws,
                                               const float* __restrict__ r_all,
                                               const float* __restrict__ part,
                                               void* __restrict__ out,
                                               int t) {
    if (t > get_tpred(Tpred)) return;
    int isf32 = flag[0];
    int tid = threadIdx.x;
    int r0 = blockIdx.x * 4;
    __shared__ __align__(16) float zT[384][4];   // z transposed: [k][local row]
    __shared__ float g2[4][4][256];              // [ksplit][row][col] partials
    // phase A: build zT = [r | e | h] for the block's 4 rows
    for (int idx = tid; idx < 1536; idx += 1024) {
        int r = idx / 384, k = idx - r * 384;
        int grow = r0 + r;
        float v;
        if (k < 64) {
            v = r_all[((long)t * 1024 + grow) * 64 + k];
        } else if (k < 320) {
            int col = k - 64;
            const float* pp = part + grow * 256 + col;
            float s0 = pp[0 * 262144] + pp[1 * 262144];
            float s1 = pp[2 * 262144] + pp[3 * 262144];
            float s2 = pp[4 * 262144] + pp[5 * 262144];
            float s3 = pp[6 * 262144] + pp[7 * 262144];
            v = fmaxf(ldin(bsoc, col, isf32) + ((s0 + s1) + (s2 + s3)), 0.f);
        } else {
            v = h_ws[grow * 64 + (k - 320)];
        }
        zT[k][r] = v;
    }
    __syncthreads();
    // phase B: partial gates; dtype branch hoisted, unroll-8 load pipelining
    int kh = tid >> 8, col = tid & 255;
    int klo = kh * 96, khi = klo + 96;
    float a0 = 0.f, a1 = 0.f, a2 = 0.f, a3 = 0.f;
    if (isf32) {
        const float* W1 = (const float*)Wih;
        const float* W2 = (const float*)Whh;
        int kmid = khi < 320 ? khi : 320;
        #pragma unroll 8
        for (int k = klo; k < kmid; k++) {
            float wv = W1[(long)k * 256 + col];
            f32x4 zv = *(f32x4*)&zT[k][0];
            a0 += zv[0] * wv; a1 += zv[1] * wv; a2 += zv[2] * wv; a3 += zv[3] * wv;
        }
        int k2 = klo > 320 ? klo : 320;
        #pragma unroll 8
        for (int k = k2; k < khi; k++) {
            float wv = W2[(long)(k - 320) * 256 + col];
            f32x4 zv = *(f32x4*)&zT[k][0];
            a0 += zv[0] * wv; a1 += zv[1] * wv; a2 += zv[2] * wv; a3 += zv[3] * wv;
        }
    } else {
        const unsigned short* W1 = (const unsigned short*)Wih;
        const unsigned short* W2 = (const unsigned short*)Whh;
        int kmid = khi < 320 ? khi : 320;
        #pragma unroll 8
        for (int k = klo; k < kmid; k++) {
            float wv = u2f(W1[(long)k * 256 + col]);
            f32x4 zv = *(f32x4*)&zT[k][0];
            a0 += zv[0] * wv; a1 += zv[1] * wv; a2 += zv[2] * wv; a3 += zv[3] * wv;
        }
        int k2 = klo > 320 ? klo : 320;
        #pragma unroll 8
        for (int k = k2; k < khi; k++) {
            float wv = u2f(W2[(long)(k - 320) * 256 + col]);
            f32x4 zv = *(f32x4*)&zT[k][0];
            a0 += zv[0] * wv; a1 += zv[1] * wv; a2 += zv[2] * wv; a3 += zv[3] * wv;
        }
    }
    g2[kh][0][col] = a0; g2[kh][1][col] = a1;
    g2[kh][2][col] = a2; g2[kh][3][col] = a3;
    __syncthreads();
    // phase C: fold 4 K-split partials + biases
    if (tid < 256) {
        float bb = ldin(bih, tid, isf32) + ldin(bhh, tid, isf32);
        #pragma unroll
        for (int r = 0; r < 4; r++)
            g2[0][r][tid] = ((g2[0][r][tid] + g2[1][r][tid])
                           + (g2[2][r][tid] + g2[3][r][tid])) + bb;
    }
    __syncthreads();
    // phase D: LSTM cell + output (4 rows x 64 lanes)
    if (tid < 256) {
        int row = tid >> 6, u = tid & 63;
        int grow = r0 + row;
        float gi = g2[0][row][u];
        float gf = g2[0][row][64 + u];
        float gg = g2[0][row][128 + u];
        float go = g2[0][row][192 + u];
        float c  = c_ws[grow * 64 + u];
        float si = 1.f / (1.f + __expf(-gi));
        float sf = 1.f / (1.f + __expf(-gf));
        float so = 1.f / (1.f + __expf(-go));
        float cn = sf * c + si * tanhf(gg);
        float hn = so * tanhf(cn);
        c_ws[grow * 64 + u] = cn;
        h_ws[grow * 64 + u] = hn;
        float p0 = hn * ldin(Wout, u * 2 + 0, isf32);
        float p1 = hn * ldin(Wout, u * 2 + 1, isf32);
        #pragma unroll
        for (int o = 32; o >= 1; o >>= 1) {
            p0 += __shfl_xor(p0, o);
            p1 += __shfl_xor(p1, o);
        }
        if (u == 0) {
            int m = masks[t * 1024 + grow];
            float o0 = 0.f, o1 = 0.f;
            if (m != 0) {
                bool appear = (t > 3) && (masks[(t - 3) * 1024 + grow] == 0);
                if (appear) {
                    o0 = ldin(Y, (t * 1024 + grow) * 2 + 0, isf32);
                    o1 = ldin(Y, (t * 1024 + grow) * 2 + 1, isf32);
                } else {
                    o0 = p0 + ldin(bout, 0, isf32);
                    o1 = p1 + ldin(bout, 1, isf32);
                }
            }
            if (!(o0 == o0)) o0 = 0.f;            // sanitize: finite diagnostics
            if (!(o1 == o1)) o1 = 0.f;
            int ofs = (t * 1024 + grow) * 2;
            if (isf32) {
                ((float*)out)[ofs + 0] = o0;
                ((float*)out)[ofs + 1] = o1;
            } else {
                ((unsigned short*)out)[ofs + 0] = f2b(o0);
                ((unsigned short*)out)[ofs + 1] = f2b(o1);
            }
        }
    }
}

extern "C" void kernel_launch(void* const* d_in, const int* in_sizes, int n_in,
                              void* d_out, int out_size, void* d_ws, size_t ws_size,
                              hipStream_t stream) {
    (void)in_sizes; (void)n_in; (void)out_size; (void)ws_size;
    const void* X     = d_in[0];
    const int*  masks = (const int*)d_in[1];
    const void* h0    = d_in[2];
    const void* c0    = d_in[3];
    const void* Y     = d_in[4];
    // d_in[5] = T_obs (unused by reference)
    const int*  Tpred = (const int*)d_in[6];
    const void* Wemb  = d_in[7];
    const void* bemb  = d_in[8];
    const void* Wsoc  = d_in[9];
    const void* bsoc  = d_in[10];
    const void* Wih   = d_in[11];
    const void* bih   = d_in[12];
    const void* Whh   = d_in[13];
    const void* bhh   = d_in[14];
    const void* Wout  = d_in[15];
    const void* bout  = d_in[16];

    char* ws = (char*)d_ws;
    float*          h_ws  = (float*)(ws + 0);
    float*          c_ws  = (float*)(ws + 262144);
    unsigned short* Wt2   = (unsigned short*)(ws + 1835008);
    unsigned short* Hbuf  = (unsigned short*)(ws + 3932160);
    int*            flag  = (int*)(ws + 11141120);
    float*          part  = (float*)(ws + 16777216);
    float*          r_all = (float*)(ws + 33554432);
    unsigned short* offs  = (unsigned short*)(ws + 41943040);
    unsigned short* ents  = (unsigned short*)(ws + 50331648);

    k_detect<<<1, 256, 0, stream>>>(Wsoc, flag);
    k_transpose<<<128, 256, 0, stream>>>(Wsoc, Wt2, flag);
    k_init<<<48, 256, 0, stream>>>(d_out, h0, c0, h_ws, c_ws, flag);
    k_codes<<<8192, 256, 0, stream>>>(X, masks, Wemb, bemb, Tpred, flag,
                                      r_all, offs, ents);
    for (int t = 0; t < 32; t++) {
        k_pool<<<1024, 256, 0, stream>>>(masks, Tpred, h_ws, offs, ents, Hbuf, t);
        k_gemm<<<512, 256, 0, stream>>>(Hbuf, Wt2, Tpred, part, t);
        k_cell<<<256, 1024, 0, stream>>>(masks, Y, bsoc, Wih, bih, Whh, bhh,
                                         Wout, bout, Tpred, flag, h_ws, c_ws,
                                         r_all, part, d_out, t);
    }
}

// Round 11
// 1061.964 us; speedup vs baseline: 1.0388x; 1.0047x over previous
//
#include <hip/hip_runtime.h>
#include <hip/hip_bf16.h>

// SocialLSTM forward, MI355X gfx950.
// Dual-dtype: float inputs may be bf16 or f32; detected at runtime from W_soc.
// ws layout (bytes):
//   h_ws  f32[1024*64]      @ 0
//   c_ws  f32[1024*64]      @ 262144
//   Wt2   bf16[64][256][64] @ 1835008   (W_soc cell-major: [cell][n][k], 2 MB)
//   Hbuf  bf16[1024*3136]   @ 3932160   (49 reachable cells * 64 hid per row)
//   flag  int32             @ 11141120  (0 = bf16 inputs, 1 = f32 inputs)
//   part  f32[8][1024*256]  @ 16777216  (K-split GEMM partials, no atomics)
//   r_all f32[32][1024][64] @ 33554432  (precomputed r = relu(coords@Wemb+b))
//   offs  u16[32*1024][64]  @ 41943040  (per (t,i): 50 prefix offsets of cell lists)
//   ents  u16[32*1024][1024]@ 50331648  (per (t,i): compacted neighbor j-lists)

typedef short bf16x8 __attribute__((ext_vector_type(8)));
typedef float f32x4 __attribute__((ext_vector_type(4)));

__device__ __forceinline__ float u2f(unsigned short u) {
    union { unsigned int i; float f; } v; v.i = ((unsigned int)u) << 16; return v.f;
}
__device__ __forceinline__ unsigned short f2b(float f) {
    __hip_bfloat16 hb = __float2bfloat16(f);
    return *(unsigned short*)&hb;
}
__device__ __forceinline__ float ldin(const void* p, int idx, int isf32) {
    return isf32 ? ((const float*)p)[idx] : u2f(((const unsigned short*)p)[idx]);
}
__device__ __forceinline__ int get_tpred(const int* p) {
    int v = p[0];
    if (v >= 0 && v <= 64) return v;
    float f = ((const float*)p)[0];
    if (f >= 0.f && f <= 64.f) return (int)f;
    float g = u2f(((const unsigned short*)p)[0]);
    if (g >= 0.f && g <= 64.f) return (int)g;
    return 31;
}

// ---------------- dtype detector: bf16-decode W_soc, look for huge/NaN -----
__global__ __launch_bounds__(256) void k_detect(const void* __restrict__ Wsoc,
                                                int* __restrict__ flag) {
    __shared__ int f;
    int tid = threadIdx.x;
    if (tid == 0) f = 0;
    __syncthreads();
    const unsigned short* p = (const unsigned short*)Wsoc;
    #pragma unroll
    for (int k = 0; k < 4; k++) {
        float v = u2f(p[tid * 4 + k]);
        if (!(v == v) || fabsf(v) > 1e20f) f = 1;   // same-address LDS write, benign
    }
    __syncthreads();
    if (tid == 0) flag[0] = f;
}

// ------- one-time: W_soc (4096x256) -> Wt2 bf16 cell-major [cell][n][k] ----
__global__ __launch_bounds__(256) void k_transpose(const void* __restrict__ Wsoc,
                                                   unsigned short* __restrict__ Wt2,
                                                   const int* __restrict__ flag) {
    __shared__ __align__(16) unsigned short tile[32 * 264];
    int isf32 = flag[0];
    int b = blockIdx.x, tid = threadIdx.x;
    int k0 = b * 32;
    if (isf32) {
        const float* W = (const float*)Wsoc;
        #pragma unroll
        for (int p = 0; p < 4; p++) {
            int kk = (tid >> 5) + p * 8;
            int n8 = (tid & 31) * 8;
            #pragma unroll
            for (int q = 0; q < 8; q++)
                tile[kk * 264 + n8 + q] = f2b(W[(k0 + kk) * 256 + n8 + q]);
        }
    } else {
        const unsigned short* W = (const unsigned short*)Wsoc;
        #pragma unroll
        for (int p = 0; p < 4; p++) {
            int kk = (tid >> 5) + p * 8;
            int n8 = (tid & 31) * 8;
            *(uint4*)&tile[kk * 264 + n8] = *(const uint4*)(W + (k0 + kk) * 256 + n8);
        }
    }
    __syncthreads();
    int n = tid;
    unsigned int packed[16];
    #pragma unroll
    for (int q = 0; q < 16; q++) {
        unsigned int lo = tile[(2 * q) * 264 + n];
        unsigned int hi = tile[(2 * q + 1) * 264 + n];
        packed[q] = lo | (hi << 16);
    }
    int craw = k0 >> 6, kk0 = k0 & 63;
    uint4* dst = (uint4*)(Wt2 + (long)craw * 16384 + (long)n * 64 + kk0);
    #pragma unroll
    for (int p = 0; p < 4; p++)
        dst[p] = make_uint4(packed[4*p], packed[4*p+1], packed[4*p+2], packed[4*p+3]);
}

// ---------------- one-time: zero d_out (dtype-sized), h0/c0 -> f32 ---------
__global__ __launch_bounds__(256) void k_init(void* __restrict__ out,
                                              const void* __restrict__ hin,
                                              const void* __restrict__ cin,
                                              float* __restrict__ h_ws,
                                              float* __restrict__ c_ws,
                                              const int* __restrict__ flag) {
    int isf32 = flag[0];
    int b = blockIdx.x, tid = threadIdx.x;
    if (b < 16) {
        uint4 z = make_uint4(0u, 0u, 0u, 0u);
        uint4* p = (uint4*)out;
        int n16 = isf32 ? 16384 : 8192;          // 65536 elems * 4 or 2 bytes / 16
        for (int idx = b * 256 + tid; idx < n16; idx += 4096) p[idx] = z;
    } else {
        int sb = b - 16;
        const void* src = (sb < 16) ? hin : cin;
        float* dst = (sb < 16) ? h_ws : c_ws;
        sb &= 15;
        int base = (sb * 256 + tid) * 16;
        #pragma unroll
        for (int p = 0; p < 16; p++) dst[base + p] = ldin(src, base + p, isf32);
    }
}

// ---------------- one-time: codes, 4 agents/block, single merged pass ------
// grid 8192: t = bid>>8, agents i = (bid&255)*4 .. +3. All 4 agents' count/
// scan/scatter phases run CONCURRENTLY: atomics into 4 separate cnt rows,
// one barrier, 4 parallel wave-scans (wave a scans agent a), one barrier,
// scatter. 3 barriers total vs 13 serial-per-agent (R10).
__global__ __launch_bounds__(256) void k_codes(const void* __restrict__ X,
                                               const int* __restrict__ masks,
                                               const void* __restrict__ Wemb,
                                               const void* __restrict__ bemb,
                                               const int* __restrict__ Tpred,
                                               const int* __restrict__ flag,
                                               float* __restrict__ r_all,
                                               unsigned short* __restrict__ offs,
                                               unsigned short* __restrict__ ents) {
    int bid = blockIdx.x;
    int t = bid >> 8, ig = bid & 255;
    if (t > get_tpred(Tpred)) return;
    int isf32 = flag[0];
    int tid = threadIdx.x;
    __shared__ float sx[1024], sy[1024];
    __shared__ unsigned char sm[1024];
    __shared__ int cnt[4][52];
    __shared__ unsigned short off_s[4][52];
    const int* mrow = masks + t * 1024;
    #pragma unroll
    for (int p = 0; p < 4; p++) {
        int j = tid + p * 256;
        sm[j] = (unsigned char)(mrow[j] != 0);
        float x, y;
        if (isf32) {
            float2 xy = *(const float2*)((const float*)X + ((long)(t * 1024 + j)) * 4 + 2);
            x = xy.x; y = xy.y;
        } else {
            unsigned int u = *(const unsigned int*)((const unsigned short*)X + ((long)(t * 1024 + j)) * 4 + 2);
            x = u2f((unsigned short)(u & 0xFFFF));
            y = u2f((unsigned short)(u >> 16));
        }
        sx[j] = x; sy[j] = y;
    }
    if (tid < 208) ((int*)cnt)[tid] = 0;      // 4*52
    __syncthreads();
    {   // r = relu(coords@Wemb + bemb) for the 4 agents (thread a=tid>>6,u=tid&63)
        int a = tid >> 6, u = tid & 63;
        int i = ig * 4 + a;
        float v = ldin(Wemb, u, isf32) * sx[i] + ldin(Wemb, 64 + u, isf32) * sy[i]
                + ldin(bemb, u, isf32);
        r_all[((long)t * 1024 + i) * 64 + u] = fmaxf(v, 0.f);
    }
    float cix[4], ciy[4];
    int act[4];
    #pragma unroll
    for (int a = 0; a < 4; a++) {
        int i = ig * 4 + a;
        act[a] = sm[i];
        cix[a] = sx[i]; ciy[a] = sy[i];
    }
    signed char cc[16];
    unsigned short rk[16];
    #pragma unroll
    for (int p = 0; p < 4; p++) {
        int j = tid + p * 256;
        int smj = sm[j];
        float xj = sx[j], yj = sy[j];
        #pragma unroll
        for (int a = 0; a < 4; a++) {
            int idx = a * 4 + p;
            cc[idx] = -1;
            if (act[a] && smj && j != (ig * 4 + a)) {
                float dx = xj - cix[a], dy = yj - ciy[a];
                int g0 = (int)dx, g1 = (int)dy;   // trunc toward zero == jnp.trunc
                if (g0 >= -3 && g0 <= 3 && g1 >= -3 && g1 <= 3) {
                    int c = (g0 + 3) * 7 + (g1 + 3);      // dense 0..48
                    cc[idx] = (signed char)c;
                    rk[idx] = (unsigned short)atomicAdd(&cnt[a][c], 1);
                }
            }
        }
    }
    __syncthreads();
    {   // 4 parallel wave-scans: wave wv computes agent wv's exclusive prefix
        int wv = tid >> 6, ln = tid & 63;
        int v = (ln < 49) ? cnt[wv][ln] : 0;
        int x = v;
        #pragma unroll
        for (int o = 1; o < 64; o <<= 1) {
            int y = __shfl_up(x, o);
            if (ln >= o) x += y;
        }
        if (ln < 49) off_s[wv][ln] = (unsigned short)(x - v);
        if (ln == 48) off_s[wv][49] = (unsigned short)x;
    }
    __syncthreads();
    #pragma unroll
    for (int a = 0; a < 4; a++) {
        unsigned short* eb = ents + ((long)t * 1024 + ig * 4 + a) * 1024;
        #pragma unroll
        for (int p = 0; p < 4; p++) {
            int idx = a * 4 + p;
            if (cc[idx] >= 0)
                eb[off_s[a][cc[idx]] + rk[idx]] = (unsigned short)(tid + p * 256);
        }
    }
    if (tid < 200) {   // offs for all 4 agents (masked agents get zeros, unread)
        int a = tid / 50, ix = tid - a * 50;
        offs[((long)t * 1024 + ig * 4 + a) * 64 + ix] = off_s[a][ix];
    }
}

// ---------------- per step: pure gather-accumulate pooling -> Hbuf ---------
// 1024 blocks (one per agent) keeps ~16 waves/CU of independent gather work
// in flight — this phase is latency-bound, parallelism is the currency.
// (R4-verified fastest variant.)
__global__ __launch_bounds__(256) void k_pool(const int* __restrict__ masks,
                                              const int* __restrict__ Tpred,
                                              const float* __restrict__ h_ws,
                                              const unsigned short* __restrict__ offs,
                                              const unsigned short* __restrict__ ents,
                                              unsigned short* __restrict__ Hbuf,
                                              int t) {
    if (t > get_tpred(Tpred)) return;
    int i = blockIdx.x, tid = threadIdx.x;
    long hb_base = (long)i * 3136;
    if (masks[t * 1024 + i] == 0) {   // block-uniform: H row is all zeros
        unsigned int* hp = (unsigned int*)(Hbuf + hb_base);
        for (int idx = tid; idx < 1568; idx += 256) hp[idx] = 0u;
        return;
    }
    __shared__ __align__(16) unsigned short el[1024];
    __shared__ unsigned short of[52];
    if (tid < 50) of[tid] = offs[((long)t * 1024 + i) * 64 + tid];
    {
        const uint4* src = (const uint4*)(ents + ((long)t * 1024 + i) * 1024);
        uint4* dst = (uint4*)el;
        if (tid < 128) dst[tid] = src[tid];   // stage full list; tail garbage unread
    }
    __syncthreads();
    int w = tid >> 6, lane = tid & 63;
    for (int c = w; c < 49; c += 4) {       // round-robin cells over 4 waves
        int k = of[c], n = of[c + 1];
        float acc = 0.f;
        for (; k + 8 <= n; k += 8) {        // 8 loads in flight per group
            int j0 = el[k], j1 = el[k + 1], j2 = el[k + 2], j3 = el[k + 3];
            int j4 = el[k + 4], j5 = el[k + 5], j6 = el[k + 6], j7 = el[k + 7];
            float v0 = h_ws[j0 * 64 + lane];
            float v1 = h_ws[j1 * 64 + lane];
            float v2 = h_ws[j2 * 64 + lane];
            float v3 = h_ws[j3 * 64 + lane];
            float v4 = h_ws[j4 * 64 + lane];
            float v5 = h_ws[j5 * 64 + lane];
            float v6 = h_ws[j6 * 64 + lane];
            float v7 = h_ws[j7 * 64 + lane];
            acc += ((v0 + v1) + (v2 + v3)) + ((v4 + v5) + (v6 + v7));
        }
        for (; k < n; k++) acc += h_ws[el[k] * 64 + lane];
        Hbuf[hb_base + c * 64 + lane] = f2b(acc);
    }
}

// ---------------- per step: part[s] = H @ W_soc slice (MFMA, dbuf LDS) -----
// grid 512: ch = bid&3 (64-col slice), s = (bid>>2)&7 (K-split), rb = bid>>5.
// B-tile staged from cell-major Wt2: fully contiguous per cell. (R4-verified.)
__global__ __launch_bounds__(256) void k_gemm(const unsigned short* __restrict__ Hbuf,
                                              const unsigned short* __restrict__ Wt2,
                                              const int* __restrict__ Tpred,
                                              float* __restrict__ part,
                                              int t) {
    if (t > get_tpred(Tpred)) return;
    int bid = blockIdx.x, tid = threadIdx.x;
    int ch = bid & 3, s = (bid >> 2) & 7, rb = bid >> 5;
    int row0 = rb * 64, col0 = ch * 64;
    int m0 = (49 * s) >> 3, m1 = (49 * (s + 1)) >> 3;   // 6,6,6,6,6,6,6,7 cells
    __shared__ __align__(16) short Asm[2][64 * 72];   // double-buffered
    __shared__ __align__(16) short Bsm[2][64 * 72];
    int w = tid >> 6, lane = tid & 63;
    int wrow = (w & 1) * 32, wcol = (w >> 1) * 32;
    int mrow = lane & 15, q = lane >> 4;
    int row = tid >> 2, seg = tid & 3;
    const unsigned short* Arow = Hbuf + (long)(row0 + row) * 3136;
    const long boff = (long)(col0 + row) * 64;
    f32x4 acc[2][2];
    f32x4 zz = {0.f, 0.f, 0.f, 0.f};
    #pragma unroll
    for (int a = 0; a < 2; a++)
        #pragma unroll
        for (int b = 0; b < 2; b++) acc[a][b] = zz;
    uint4 ra0, ra1, rb0, rb1;
    {   // prologue: load cell m0
        int craw = ((m0 / 7) * 8 + (m0 % 7) + 9);
        const unsigned short* Bc = Wt2 + (long)craw * 16384 + boff;
        ra0 = *(const uint4*)(Arow + m0 * 64 + seg * 8);
        ra1 = *(const uint4*)(Arow + m0 * 64 + (seg + 4) * 8);
        rb0 = *(const uint4*)(Bc + seg * 8);
        rb1 = *(const uint4*)(Bc + (seg + 4) * 8);
        *(uint4*)&Asm[0][row * 72 + seg * 8] = ra0;
        *(uint4*)&Asm[0][row * 72 + (seg + 4) * 8] = ra1;
        *(uint4*)&Bsm[0][row * 72 + seg * 8] = rb0;
        *(uint4*)&Bsm[0][row * 72 + (seg + 4) * 8] = rb1;
    }
    __syncthreads();
    for (int m = m0; m < m1; m++) {
        int p = (m - m0) & 1;
        if (m + 1 < m1) {   // prefetch next cell into the other buffer
            int mm = m + 1;
            int craw = ((mm / 7) * 8 + (mm % 7) + 9);
            const unsigned short* Bc = Wt2 + (long)craw * 16384 + boff;
            ra0 = *(const uint4*)(Arow + mm * 64 + seg * 8);
            ra1 = *(const uint4*)(Arow + mm * 64 + (seg + 4) * 8);
            rb0 = *(const uint4*)(Bc + seg * 8);
            rb1 = *(const uint4*)(Bc + (seg + 4) * 8);
            *(uint4*)&Asm[p ^ 1][row * 72 + seg * 8] = ra0;
            *(uint4*)&Asm[p ^ 1][row * 72 + (seg + 4) * 8] = ra1;
            *(uint4*)&Bsm[p ^ 1][row * 72 + seg * 8] = rb0;
            *(uint4*)&Bsm[p ^ 1][row * 72 + (seg + 4) * 8] = rb1;
        }
        #pragma unroll
        for (int kc = 0; kc < 2; kc++) {
            bf16x8 a0 = *(bf16x8*)&Asm[p][(wrow +      mrow) * 72 + kc * 32 + q * 8];
            bf16x8 a1 = *(bf16x8*)&Asm[p][(wrow + 16 + mrow) * 72 + kc * 32 + q * 8];
            #pragma unroll
            for (int ct = 0; ct < 2; ct++) {
                bf16x8 bv = *(bf16x8*)&Bsm[p][(wcol + ct * 16 + mrow) * 72 + kc * 32 + q * 8];
                acc[0][ct] = __builtin_amdgcn_mfma_f32_16x16x32_bf16(a0, bv, acc[0][ct], 0, 0, 0);
                acc[1][ct] = __builtin_amdgcn_mfma_f32_16x16x32_bf16(a1, bv, acc[1][ct], 0, 0, 0);
            }
        }
        __syncthreads();
    }
    // C/D layout: col = lane&15, row = (lane>>4)*4 + reg. Plain stores, no RMW.
    float* ps = part + (long)s * 262144;
    #pragma unroll
    for (int rt = 0; rt < 2; rt++)
        #pragma unroll
        for (int ct = 0; ct < 2; ct++)
            #pragma unroll
            for (int r = 0; r < 4; r++) {
                int grow = row0 + wrow + rt * 16 + q * 4 + r;
                int gcol = col0 + wcol + ct * 16 + mrow;
                ps[grow * 256 + gcol] = acc[rt][ct][r];
            }
}

// ---------------- per step: gates GEMV, LSTM cell, out ---------------------
// grid 256 x 1024 threads: 4 rows/block, 4-way K-split (96 k-iters each).
// 16 waves/CU + unroll-8 load pipelining. (R4/R7/R9-verified fastest variant.)
__global__ __launch_bounds__(1024) void k_cell(const int* __restrict__ masks,
                                               const void* __restrict__ Y,
                                               const void* __restrict__ bsoc,
                                               const void* __restrict__ Wih,
                                               const void* __restrict__ bih,
                                               const void* __restrict__ Whh,
                                               const void* __restrict__ bhh,
                                               const void* __restrict__ Wout,
                                               const void* __restrict__ bout,
                                               const int* __restrict__ Tpred,
                                               const int* __restrict__ flag,
                                               float* __restrict__ h_ws,
                                               float* __restrict__ c_ws,
                                               const float* __restrict__ r_all,
                                               const float* __restrict__ part,
                                               void* __restrict__ out,
                                               int t) {
    if (t > get_tpred(Tpred)) return;
    int isf32 = flag[0];
    int tid = threadIdx.x;
    int r0 = blockIdx.x * 4;
    __shared__ __align__(16) float zT[384][4];   // z transposed: [k][local row]
    __shared__ float g2[4][4][256];              // [ksplit][row][col] partials
    // phase A: build zT = [r | e | h] for the block's 4 rows
    for (int idx = tid; idx < 1536; idx += 1024) {
        int r = idx / 384, k = idx - r * 384;
        int grow = r0 + r;
        float v;
        if (k < 64) {
            v = r_all[((long)t * 1024 + grow) * 64 + k];
        } else if (k < 320) {
            int col = k - 64;
            const float* pp = part + grow * 256 + col;
            float s0 = pp[0 * 262144] + pp[1 * 262144];
            float s1 = pp[2 * 262144] + pp[3 * 262144];
            float s2 = pp[4 * 262144] + pp[5 * 262144];
            float s3 = pp[6 * 262144] + pp[7 * 262144];
            v = fmaxf(ldin(bsoc, col, isf32) + ((s0 + s1) + (s2 + s3)), 0.f);
        } else {
            v = h_ws[grow * 64 + (k - 320)];
        }
        zT[k][r] = v;
    }
    __syncthreads();
    // phase B: partial gates; dtype branch hoisted, unroll-8 load pipelining
    int kh = tid >> 8, col = tid & 255;
    int klo = kh * 96, khi = klo + 96;
    float a0 = 0.f, a1 = 0.f, a2 = 0.f, a3 = 0.f;
    if (isf32) {
        const float* W1 = (const float*)Wih;
        const float* W2 = (const float*)Whh;
        int kmid = khi < 320 ? khi : 320;
        #pragma unroll 8
        for (int k = klo; k < kmid; k++) {
            float wv = W1[(long)k * 256 + col];
            f32x4 zv = *(f32x4*)&zT[k][0];
            a0 += zv[0] * wv; a1 += zv[1] * wv; a2 += zv[2] * wv; a3 += zv[3] * wv;
        }
        int k2 = klo > 320 ? klo : 320;
        #pragma unroll 8
        for (int k = k2; k < khi; k++) {
            float wv = W2[(long)(k - 320) * 256 + col];
            f32x4 zv = *(f32x4*)&zT[k][0];
            a0 += zv[0] * wv; a1 += zv[1] * wv; a2 += zv[2] * wv; a3 += zv[3] * wv;
        }
    } else {
        const unsigned short* W1 = (const unsigned short*)Wih;
        const unsigned short* W2 = (const unsigned short*)Whh;
        int kmid = khi < 320 ? khi : 320;
        #pragma unroll 8
        for (int k = klo; k < kmid; k++) {
            float wv = u2f(W1[(long)k * 256 + col]);
            f32x4 zv = *(f32x4*)&zT[k][0];
            a0 += zv[0] * wv; a1 += zv[1] * wv; a2 += zv[2] * wv; a3 += zv[3] * wv;
        }
        int k2 = klo > 320 ? klo : 320;
        #pragma unroll 8
        for (int k = k2; k < khi; k++) {
            float wv = u2f(W2[(long)(k - 320) * 256 + col]);
            f32x4 zv = *(f32x4*)&zT[k][0];
            a0 += zv[0] * wv; a1 += zv[1] * wv; a2 += zv[2] * wv; a3 += zv[3] * wv;
        }
    }
    g2[kh][0][col] = a0; g2[kh][1][col] = a1;
    g2[kh][2][col] = a2; g2[kh][3][col] = a3;
    __syncthreads();
    // phase C: fold 4 K-split partials + biases
    if (tid < 256) {
        float bb = ldin(bih, tid, isf32) + ldin(bhh, tid, isf32);
        #pragma unroll
        for (int r = 0; r < 4; r++)
            g2[0][r][tid] = ((g2[0][r][tid] + g2[1][r][tid])
                           + (g2[2][r][tid] + g2[3][r][tid])) + bb;
    }
    __syncthreads();
    // phase D: LSTM cell + output (4 rows x 64 lanes)
    if (tid < 256) {
        int row = tid >> 6, u = tid & 63;
        int grow = r0 + row;
        float gi = g2[0][row][u];
        float gf = g2[0][row][64 + u];
        float gg = g2[0][row][128 + u];
        float go = g2[0][row][192 + u];
        float c  = c_ws[grow * 64 + u];
        float si = 1.f / (1.f + __expf(-gi));
        float sf = 1.f / (1.f + __expf(-gf));
        float so = 1.f / (1.f + __expf(-go));
        float cn = sf * c + si * tanhf(gg);
        float hn = so * tanhf(cn);
        c_ws[grow * 64 + u] = cn;
        h_ws[grow * 64 + u] = hn;
        float p0 = hn * ldin(Wout, u * 2 + 0, isf32);
        float p1 = hn * ldin(Wout, u * 2 + 1, isf32);
        #pragma unroll
        for (int o = 32; o >= 1; o >>= 1) {
            p0 += __shfl_xor(p0, o);
            p1 += __shfl_xor(p1, o);
        }
        if (u == 0) {
            int m = masks[t * 1024 + grow];
            float o0 = 0.f, o1 = 0.f;
            if (m != 0) {
                bool appear = (t > 3) && (masks[(t - 3) * 1024 + grow] == 0);
                if (appear) {
                    o0 = ldin(Y, (t * 1024 + grow) * 2 + 0, isf32);
                    o1 = ldin(Y, (t * 1024 + grow) * 2 + 1, isf32);
                } else {
                    o0 = p0 + ldin(bout, 0, isf32);
                    o1 = p1 + ldin(bout, 1, isf32);
                }
            }
            if (!(o0 == o0)) o0 = 0.f;            // sanitize: finite diagnostics
            if (!(o1 == o1)) o1 = 0.f;
            int ofs = (t * 1024 + grow) * 2;
            if (isf32) {
                ((float*)out)[ofs + 0] = o0;
                ((float*)out)[ofs + 1] = o1;
            } else {
                ((unsigned short*)out)[ofs + 0] = f2b(o0);
                ((unsigned short*)out)[ofs + 1] = f2b(o1);
            }
        }
    }
}

extern "C" void kernel_launch(void* const* d_in, const int* in_sizes, int n_in,
                              void* d_out, int out_size, void* d_ws, size_t ws_size,
                              hipStream_t stream) {
    (void)in_sizes; (void)n_in; (void)out_size; (void)ws_size;
    const void* X     = d_in[0];
    const int*  masks = (const int*)d_in[1];
    const void* h0    = d_in[2];
    const void* c0    = d_in[3];
    const void* Y     = d_in[4];
    // d_in[5] = T_obs (unused by reference)
    const int*  Tpred = (const int*)d_in[6];
    const void* Wemb  = d_in[7];
    const void* bemb  = d_in[8];
    const void* Wsoc  = d_in[9];
    const void* bsoc  = d_in[10];
    const void* Wih   = d_in[11];
    const void* bih   = d_in[12];
    const void* Whh   = d_in[13];
    const void* bhh   = d_in[14];
    const void* Wout  = d_in[15];
    const void* bout  = d_in[16];

    char* ws = (char*)d_ws;
    float*          h_ws  = (float*)(ws + 0);
    float*          c_ws  = (float*)(ws + 262144);
    unsigned short* Wt2   = (unsigned short*)(ws + 1835008);
    unsigned short* Hbuf  = (unsigned short*)(ws + 3932160);
    int*            flag  = (int*)(ws + 11141120);
    float*          part  = (float*)(ws + 16777216);
    float*          r_all = (float*)(ws + 33554432);
    unsigned short* offs  = (unsigned short*)(ws + 41943040);
    unsigned short* ents  = (unsigned short*)(ws + 50331648);

    k_detect<<<1, 256, 0, stream>>>(Wsoc, flag);
    k_transpose<<<128, 256, 0, stream>>>(Wsoc, Wt2, flag);
    k_init<<<48, 256, 0, stream>>>(d_out, h0, c0, h_ws, c_ws, flag);
    k_codes<<<8192, 256, 0, stream>>>(X, masks, Wemb, bemb, Tpred, flag,
                                      r_all, offs, ents);
    for (int t = 0; t < 32; t++) {
        k_pool<<<1024, 256, 0, stream>>>(masks, Tpred, h_ws, offs, ents, Hbuf, t);
        k_gemm<<<512, 256, 0, stream>>>(Hbuf, Wt2, Tpred, part, t);
        k_cell<<<256, 1024, 0, stream>>>(masks, Y, bsoc, Wih, bih, Whh, bhh,
                                         Wout, bout, Tpred, flag, h_ws, c_ws,
                                         r_all, part, d_out, t);
    }
}

// Round 12
// 1046.278 us; speedup vs baseline: 1.0543x; 1.0150x over previous
//
#include <hip/hip_runtime.h>
#include <hip/hip_bf16.h>

// SocialLSTM forward, MI355X gfx950.
// Dual-dtype: float inputs may be bf16 or f32; detected at runtime from W_soc.
// ws layout (bytes):
//   h_ws  f32[1024*64]      @ 0
//   c_ws  f32[1024*64]      @ 262144
//   Wt2   bf16[64][256][64] @ 1835008   (W_soc cell-major: [cell][n][k], 2 MB)
//   Hbuf  bf16[1024*3136]   @ 3932160   (49 reachable cells * 64 hid per row)
//   flag  int32             @ 11141120  (0 = bf16 inputs, 1 = f32 inputs)
//   part  f32[8][1024*256]  @ 16777216  (K-split GEMM partials, no atomics)
//   r_all f32[32][1024][64] @ 33554432  (precomputed r = relu(coords@Wemb+b))
//   offs  u16[32*1024][64]  @ 41943040  (per (t,i): 50 prefix offsets of cell lists)
//   ents  u16[32*1024][1024]@ 50331648  (per (t,i): compacted neighbor j-lists)

typedef short bf16x8 __attribute__((ext_vector_type(8)));
typedef float f32x4 __attribute__((ext_vector_type(4)));

__device__ __forceinline__ float u2f(unsigned short u) {
    union { unsigned int i; float f; } v; v.i = ((unsigned int)u) << 16; return v.f;
}
__device__ __forceinline__ unsigned short f2b(float f) {
    __hip_bfloat16 hb = __float2bfloat16(f);
    return *(unsigned short*)&hb;
}
__device__ __forceinline__ float ldin(const void* p, int idx, int isf32) {
    return isf32 ? ((const float*)p)[idx] : u2f(((const unsigned short*)p)[idx]);
}
__device__ __forceinline__ int get_tpred(const int* p) {
    int v = p[0];
    if (v >= 0 && v <= 64) return v;
    float f = ((const float*)p)[0];
    if (f >= 0.f && f <= 64.f) return (int)f;
    float g = u2f(((const unsigned short*)p)[0]);
    if (g >= 0.f && g <= 64.f) return (int)g;
    return 31;
}

// ---------------- dtype detector: bf16-decode W_soc, look for huge/NaN -----
__global__ __launch_bounds__(256) void k_detect(const void* __restrict__ Wsoc,
                                                int* __restrict__ flag) {
    __shared__ int f;
    int tid = threadIdx.x;
    if (tid == 0) f = 0;
    __syncthreads();
    const unsigned short* p = (const unsigned short*)Wsoc;
    #pragma unroll
    for (int k = 0; k < 4; k++) {
        float v = u2f(p[tid * 4 + k]);
        if (!(v == v) || fabsf(v) > 1e20f) f = 1;   // same-address LDS write, benign
    }
    __syncthreads();
    if (tid == 0) flag[0] = f;
}

// ------- one-time: W_soc (4096x256) -> Wt2 bf16 cell-major [cell][n][k] ----
__global__ __launch_bounds__(256) void k_transpose(const void* __restrict__ Wsoc,
                                                   unsigned short* __restrict__ Wt2,
                                                   const int* __restrict__ flag) {
    __shared__ __align__(16) unsigned short tile[32 * 264];
    int isf32 = flag[0];
    int b = blockIdx.x, tid = threadIdx.x;
    int k0 = b * 32;
    if (isf32) {
        const float* W = (const float*)Wsoc;
        #pragma unroll
        for (int p = 0; p < 4; p++) {
            int kk = (tid >> 5) + p * 8;
            int n8 = (tid & 31) * 8;
            #pragma unroll
            for (int q = 0; q < 8; q++)
                tile[kk * 264 + n8 + q] = f2b(W[(k0 + kk) * 256 + n8 + q]);
        }
    } else {
        const unsigned short* W = (const unsigned short*)Wsoc;
        #pragma unroll
        for (int p = 0; p < 4; p++) {
            int kk = (tid >> 5) + p * 8;
            int n8 = (tid & 31) * 8;
            *(uint4*)&tile[kk * 264 + n8] = *(const uint4*)(W + (k0 + kk) * 256 + n8);
        }
    }
    __syncthreads();
    int n = tid;
    unsigned int packed[16];
    #pragma unroll
    for (int q = 0; q < 16; q++) {
        unsigned int lo = tile[(2 * q) * 264 + n];
        unsigned int hi = tile[(2 * q + 1) * 264 + n];
        packed[q] = lo | (hi << 16);
    }
    int craw = k0 >> 6, kk0 = k0 & 63;
    uint4* dst = (uint4*)(Wt2 + (long)craw * 16384 + (long)n * 64 + kk0);
    #pragma unroll
    for (int p = 0; p < 4; p++)
        dst[p] = make_uint4(packed[4*p], packed[4*p+1], packed[4*p+2], packed[4*p+3]);
}

// --------- one-time: zero d_out + Hbuf, h0/c0 -> f32 (grid 304) ------------
__global__ __launch_bounds__(256) void k_init(void* __restrict__ out,
                                              const void* __restrict__ hin,
                                              const void* __restrict__ cin,
                                              float* __restrict__ h_ws,
                                              float* __restrict__ c_ws,
                                              unsigned short* __restrict__ Hbuf,
                                              const int* __restrict__ flag) {
    int isf32 = flag[0];
    int b = blockIdx.x, tid = threadIdx.x;
    if (b < 16) {
        uint4 z = make_uint4(0u, 0u, 0u, 0u);
        uint4* p = (uint4*)out;
        int n16 = isf32 ? 16384 : 8192;          // 65536 elems * 4 or 2 bytes / 16
        for (int idx = b * 256 + tid; idx < n16; idx += 4096) p[idx] = z;
    } else if (b < 48) {
        int sb = b - 16;
        const void* src = (sb < 16) ? hin : cin;
        float* dst = (sb < 16) ? h_ws : c_ws;
        sb &= 15;
        int base = (sb * 256 + tid) * 16;
        #pragma unroll
        for (int p = 0; p < 16; p++) dst[base + p] = ldin(src, base + p, isf32);
    } else {
        // zero Hbuf once: 1024*3136*2B = 401408 uint4. k_pool then only
        // re-zeros rows on active->inactive transitions.
        uint4 z = make_uint4(0u, 0u, 0u, 0u);
        uint4* p = (uint4*)Hbuf;
        for (int idx = (b - 48) * 256 + tid; idx < 401408; idx += 65536)
            p[idx] = z;
    }
}

// ---------------- one-time: codes, 4 agents/block, single merged pass ------
// grid 8192: t = bid>>8, agents i = (bid&255)*4 .. +3. (R11-verified.)
__global__ __launch_bounds__(256) void k_codes(const void* __restrict__ X,
                                               const int* __restrict__ masks,
                                               const void* __restrict__ Wemb,
                                               const void* __restrict__ bemb,
                                               const int* __restrict__ Tpred,
                                               const int* __restrict__ flag,
                                               float* __restrict__ r_all,
                                               unsigned short* __restrict__ offs,
                                               unsigned short* __restrict__ ents) {
    int bid = blockIdx.x;
    int t = bid >> 8, ig = bid & 255;
    if (t > get_tpred(Tpred)) return;
    int isf32 = flag[0];
    int tid = threadIdx.x;
    __shared__ float sx[1024], sy[1024];
    __shared__ unsigned char sm[1024];
    __shared__ int cnt[4][52];
    __shared__ unsigned short off_s[4][52];
    const int* mrow = masks + t * 1024;
    #pragma unroll
    for (int p = 0; p < 4; p++) {
        int j = tid + p * 256;
        sm[j] = (unsigned char)(mrow[j] != 0);
        float x, y;
        if (isf32) {
            float2 xy = *(const float2*)((const float*)X + ((long)(t * 1024 + j)) * 4 + 2);
            x = xy.x; y = xy.y;
        } else {
            unsigned int u = *(const unsigned int*)((const unsigned short*)X + ((long)(t * 1024 + j)) * 4 + 2);
            x = u2f((unsigned short)(u & 0xFFFF));
            y = u2f((unsigned short)(u >> 16));
        }
        sx[j] = x; sy[j] = y;
    }
    if (tid < 208) ((int*)cnt)[tid] = 0;      // 4*52
    __syncthreads();
    {   // r = relu(coords@Wemb + bemb) for the 4 agents (thread a=tid>>6,u=tid&63)
        int a = tid >> 6, u = tid & 63;
        int i = ig * 4 + a;
        float v = ldin(Wemb, u, isf32) * sx[i] + ldin(Wemb, 64 + u, isf32) * sy[i]
                + ldin(bemb, u, isf32);
        r_all[((long)t * 1024 + i) * 64 + u] = fmaxf(v, 0.f);
    }
    float cix[4], ciy[4];
    int act[4];
    #pragma unroll
    for (int a = 0; a < 4; a++) {
        int i = ig * 4 + a;
        act[a] = sm[i];
        cix[a] = sx[i]; ciy[a] = sy[i];
    }
    signed char cc[16];
    unsigned short rk[16];
    #pragma unroll
    for (int p = 0; p < 4; p++) {
        int j = tid + p * 256;
        int smj = sm[j];
        float xj = sx[j], yj = sy[j];
        #pragma unroll
        for (int a = 0; a < 4; a++) {
            int idx = a * 4 + p;
            cc[idx] = -1;
            if (act[a] && smj && j != (ig * 4 + a)) {
                float dx = xj - cix[a], dy = yj - ciy[a];
                int g0 = (int)dx, g1 = (int)dy;   // trunc toward zero == jnp.trunc
                if (g0 >= -3 && g0 <= 3 && g1 >= -3 && g1 <= 3) {
                    int c = (g0 + 3) * 7 + (g1 + 3);      // dense 0..48
                    cc[idx] = (signed char)c;
                    rk[idx] = (unsigned short)atomicAdd(&cnt[a][c], 1);
                }
            }
        }
    }
    __syncthreads();
    {   // 4 parallel wave-scans: wave wv computes agent wv's exclusive prefix
        int wv = tid >> 6, ln = tid & 63;
        int v = (ln < 49) ? cnt[wv][ln] : 0;
        int x = v;
        #pragma unroll
        for (int o = 1; o < 64; o <<= 1) {
            int y = __shfl_up(x, o);
            if (ln >= o) x += y;
        }
        if (ln < 49) off_s[wv][ln] = (unsigned short)(x - v);
        if (ln == 48) off_s[wv][49] = (unsigned short)x;
    }
    __syncthreads();
    #pragma unroll
    for (int a = 0; a < 4; a++) {
        unsigned short* eb = ents + ((long)t * 1024 + ig * 4 + a) * 1024;
        #pragma unroll
        for (int p = 0; p < 4; p++) {
            int idx = a * 4 + p;
            if (cc[idx] >= 0)
                eb[off_s[a][cc[idx]] + rk[idx]] = (unsigned short)(tid + p * 256);
        }
    }
    if (tid < 200) {   // offs for all 4 agents (masked agents get zeros, unread)
        int a = tid / 50, ix = tid - a * 50;
        offs[((long)t * 1024 + ig * 4 + a) * 64 + ix] = off_s[a][ix];
    }
}

// ---------------- per step: pure gather-accumulate pooling -> Hbuf ---------
// 1024 blocks (one per agent). Inactive agents: Hbuf row already zero unless
// the agent was ACTIVE at t-1 (active agents rewrite all 49 cells each step;
// k_init pre-zeroes Hbuf). Zero-fill only on active->inactive transitions.
__global__ __launch_bounds__(256) void k_pool(const int* __restrict__ masks,
                                              const int* __restrict__ Tpred,
                                              const float* __restrict__ h_ws,
                                              const unsigned short* __restrict__ offs,
                                              const unsigned short* __restrict__ ents,
                                              unsigned short* __restrict__ Hbuf,
                                              int t) {
    if (t > get_tpred(Tpred)) return;
    int i = blockIdx.x, tid = threadIdx.x;
    long hb_base = (long)i * 3136;
    if (masks[t * 1024 + i] == 0) {
        if (t == 0 || masks[(t - 1) * 1024 + i] == 0) return;  // already zero
        unsigned int* hp = (unsigned int*)(Hbuf + hb_base);    // clear stale row
        for (int idx = tid; idx < 1568; idx += 256) hp[idx] = 0u;
        return;
    }
    __shared__ __align__(16) unsigned short el[1024];
    __shared__ unsigned short of[52];
    if (tid < 50) of[tid] = offs[((long)t * 1024 + i) * 64 + tid];
    {
        const uint4* src = (const uint4*)(ents + ((long)t * 1024 + i) * 1024);
        uint4* dst = (uint4*)el;
        if (tid < 128) dst[tid] = src[tid];   // stage full list; tail garbage unread
    }
    __syncthreads();
    int w = tid >> 6, lane = tid & 63;
    for (int c = w; c < 49; c += 4) {       // round-robin cells over 4 waves
        int k = of[c], n = of[c + 1];
        float acc = 0.f;
        for (; k + 8 <= n; k += 8) {        // 8 loads in flight per group
            int j0 = el[k], j1 = el[k + 1], j2 = el[k + 2], j3 = el[k + 3];
            int j4 = el[k + 4], j5 = el[k + 5], j6 = el[k + 6], j7 = el[k + 7];
            float v0 = h_ws[j0 * 64 + lane];
            float v1 = h_ws[j1 * 64 + lane];
            float v2 = h_ws[j2 * 64 + lane];
            float v3 = h_ws[j3 * 64 + lane];
            float v4 = h_ws[j4 * 64 + lane];
            float v5 = h_ws[j5 * 64 + lane];
            float v6 = h_ws[j6 * 64 + lane];
            float v7 = h_ws[j7 * 64 + lane];
            acc += ((v0 + v1) + (v2 + v3)) + ((v4 + v5) + (v6 + v7));
        }
        for (; k < n; k++) acc += h_ws[el[k] * 64 + lane];
        Hbuf[hb_base + c * 64 + lane] = f2b(acc);
    }
}

// ---------------- per step: part[s] = H @ W_soc slice (MFMA, dbuf LDS) -----
// grid 512: ch = bid&3 (64-col slice), s = (bid>>2)&7 (K-split), rb = bid>>5.
// B-tile staged from cell-major Wt2: fully contiguous per cell. (R4-verified.)
__global__ __launch_bounds__(256) void k_gemm(const unsigned short* __restrict__ Hbuf,
                                              const unsigned short* __restrict__ Wt2,
                                              const int* __restrict__ Tpred,
                                              float* __restrict__ part,
                                              int t) {
    if (t > get_tpred(Tpred)) return;
    int bid = blockIdx.x, tid = threadIdx.x;
    int ch = bid & 3, s = (bid >> 2) & 7, rb = bid >> 5;
    int row0 = rb * 64, col0 = ch * 64;
    int m0 = (49 * s) >> 3, m1 = (49 * (s + 1)) >> 3;   // 6,6,6,6,6,6,6,7 cells
    __shared__ __align__(16) short Asm[2][64 * 72];   // double-buffered
    __shared__ __align__(16) short Bsm[2][64 * 72];
    int w = tid >> 6, lane = tid & 63;
    int wrow = (w & 1) * 32, wcol = (w >> 1) * 32;
    int mrow = lane & 15, q = lane >> 4;
    int row = tid >> 2, seg = tid & 3;
    const unsigned short* Arow = Hbuf + (long)(row0 + row) * 3136;
    const long boff = (long)(col0 + row) * 64;
    f32x4 acc[2][2];
    f32x4 zz = {0.f, 0.f, 0.f, 0.f};
    #pragma unroll
    for (int a = 0; a < 2; a++)
        #pragma unroll
        for (int b = 0; b < 2; b++) acc[a][b] = zz;
    uint4 ra0, ra1, rb0, rb1;
    {   // prologue: load cell m0
        int craw = ((m0 / 7) * 8 + (m0 % 7) + 9);
        const unsigned short* Bc = Wt2 + (long)craw * 16384 + boff;
        ra0 = *(const uint4*)(Arow + m0 * 64 + seg * 8);
        ra1 = *(const uint4*)(Arow + m0 * 64 + (seg + 4) * 8);
        rb0 = *(const uint4*)(Bc + seg * 8);
        rb1 = *(const uint4*)(Bc + (seg + 4) * 8);
        *(uint4*)&Asm[0][row * 72 + seg * 8] = ra0;
        *(uint4*)&Asm[0][row * 72 + (seg + 4) * 8] = ra1;
        *(uint4*)&Bsm[0][row * 72 + seg * 8] = rb0;
        *(uint4*)&Bsm[0][row * 72 + (seg + 4) * 8] = rb1;
    }
    __syncthreads();
    for (int m = m0; m < m1; m++) {
        int p = (m - m0) & 1;
        if (m + 1 < m1) {   // prefetch next cell into the other buffer
            int mm = m + 1;
            int craw = ((mm / 7) * 8 + (mm % 7) + 9);
            const unsigned short* Bc = Wt2 + (long)craw * 16384 + boff;
            ra0 = *(const uint4*)(Arow + mm * 64 + seg * 8);
            ra1 = *(const uint4*)(Arow + mm * 64 + (seg + 4) * 8);
            rb0 = *(const uint4*)(Bc + seg * 8);
            rb1 = *(const uint4*)(Bc + (seg + 4) * 8);
            *(uint4*)&Asm[p ^ 1][row * 72 + seg * 8] = ra0;
            *(uint4*)&Asm[p ^ 1][row * 72 + (seg + 4) * 8] = ra1;
            *(uint4*)&Bsm[p ^ 1][row * 72 + seg * 8] = rb0;
            *(uint4*)&Bsm[p ^ 1][row * 72 + (seg + 4) * 8] = rb1;
        }
        #pragma unroll
        for (int kc = 0; kc < 2; kc++) {
            bf16x8 a0 = *(bf16x8*)&Asm[p][(wrow +      mrow) * 72 + kc * 32 + q * 8];
            bf16x8 a1 = *(bf16x8*)&Asm[p][(wrow + 16 + mrow) * 72 + kc * 32 + q * 8];
            #pragma unroll
            for (int ct = 0; ct < 2; ct++) {
                bf16x8 bv = *(bf16x8*)&Bsm[p][(wcol + ct * 16 + mrow) * 72 + kc * 32 + q * 8];
                acc[0][ct] = __builtin_amdgcn_mfma_f32_16x16x32_bf16(a0, bv, acc[0][ct], 0, 0, 0);
                acc[1][ct] = __builtin_amdgcn_mfma_f32_16x16x32_bf16(a1, bv, acc[1][ct], 0, 0, 0);
            }
        }
        __syncthreads();
    }
    // C/D layout: col = lane&15, row = (lane>>4)*4 + reg. Plain stores, no RMW.
    float* ps = part + (long)s * 262144;
    #pragma unroll
    for (int rt = 0; rt < 2; rt++)
        #pragma unroll
        for (int ct = 0; ct < 2; ct++)
            #pragma unroll
            for (int r = 0; r < 4; r++) {
                int grow = row0 + wrow + rt * 16 + q * 4 + r;
                int gcol = col0 + wcol + ct * 16 + mrow;
                ps[grow * 256 + gcol] = acc[rt][ct][r];
            }
}

// ---------------- per step: gates GEMV, LSTM cell, out ---------------------
// grid 256 x 1024 threads: 4 rows/block, 4-way K-split (96 k-iters each).
// 16 waves/CU + unroll-8 load pipelining. (R4/R7/R9-verified fastest variant.)
__global__ __launch_bounds__(1024) void k_cell(const int* __restrict__ masks,
                                               const void* __restrict__ Y,
                                               const void* __restrict__ bsoc,
                                               const void* __restrict__ Wih,
                                               const void* __restrict__ bih,
                                               const void* __restrict__ Whh,
                                               const void* __restrict__ bhh,
                                               const void* __restrict__ Wout,
                                               const void* __restrict__ bout,
                                               const int* __restrict__ Tpred,
                                               const int* __restrict__ flag,
                                               float* __restrict__ h_ws,
                                               float* __restrict__ c_ws,
                                               const float* __restrict__ r_all,
                                               const float* __restrict__ part,
                                               void* __restrict__ out,
                                               int t) {
    if (t > get_tpred(Tpred)) return;
    int isf32 = flag[0];
    int tid = threadIdx.x;
    int r0 = blockIdx.x * 4;
    __shared__ __align__(16) float zT[384][4];   // z transposed: [k][local row]
    __shared__ float g2[4][4][256];              // [ksplit][row][col] partials
    // phase A: build zT = [r | e | h] for the block's 4 rows
    for (int idx = tid; idx < 1536; idx += 1024) {
        int r = idx / 384, k = idx - r * 384;
        int grow = r0 + r;
        float v;
        if (k < 64) {
            v = r_all[((long)t * 1024 + grow) * 64 + k];
        } else if (k < 320) {
            int col = k - 64;
            const float* pp = part + grow * 256 + col;
            float s0 = pp[0 * 262144] + pp[1 * 262144];
            float s1 = pp[2 * 262144] + pp[3 * 262144];
            float s2 = pp[4 * 262144] + pp[5 * 262144];
            float s3 = pp[6 * 262144] + pp[7 * 262144];
            v = fmaxf(ldin(bsoc, col, isf32) + ((s0 + s1) + (s2 + s3)), 0.f);
        } else {
            v = h_ws[grow * 64 + (k - 320)];
        }
        zT[k][r] = v;
    }
    __syncthreads();
    // phase B: partial gates; dtype branch hoisted, unroll-8 load pipelining
    int kh = tid >> 8, col = tid & 255;
    int klo = kh * 96, khi = klo + 96;
    float a0 = 0.f, a1 = 0.f, a2 = 0.f, a3 = 0.f;
    if (isf32) {
        const float* W1 = (const float*)Wih;
        const float* W2 = (const float*)Whh;
        int kmid = khi < 320 ? khi : 320;
        #pragma unroll 8
        for (int k = klo; k < kmid; k++) {
            float wv = W1[(long)k * 256 + col];
            f32x4 zv = *(f32x4*)&zT[k][0];
            a0 += zv[0] * wv; a1 += zv[1] * wv; a2 += zv[2] * wv; a3 += zv[3] * wv;
        }
        int k2 = klo > 320 ? klo : 320;
        #pragma unroll 8
        for (int k = k2; k < khi; k++) {
            float wv = W2[(long)(k - 320) * 256 + col];
            f32x4 zv = *(f32x4*)&zT[k][0];
            a0 += zv[0] * wv; a1 += zv[1] * wv; a2 += zv[2] * wv; a3 += zv[3] * wv;
        }
    } else {
        const unsigned short* W1 = (const unsigned short*)Wih;
        const unsigned short* W2 = (const unsigned short*)Whh;
        int kmid = khi < 320 ? khi : 320;
        #pragma unroll 8
        for (int k = klo; k < kmid; k++) {
            float wv = u2f(W1[(long)k * 256 + col]);
            f32x4 zv = *(f32x4*)&zT[k][0];
            a0 += zv[0] * wv; a1 += zv[1] * wv; a2 += zv[2] * wv; a3 += zv[3] * wv;
        }
        int k2 = klo > 320 ? klo : 320;
        #pragma unroll 8
        for (int k = k2; k < khi; k++) {
            float wv = u2f(W2[(long)(k - 320) * 256 + col]);
            f32x4 zv = *(f32x4*)&zT[k][0];
            a0 += zv[0] * wv; a1 += zv[1] * wv; a2 += zv[2] * wv; a3 += zv[3] * wv;
        }
    }
    g2[kh][0][col] = a0; g2[kh][1][col] = a1;
    g2[kh][2][col] = a2; g2[kh][3][col] = a3;
    __syncthreads();
    // phase C: fold 4 K-split partials + biases
    if (tid < 256) {
        float bb = ldin(bih, tid, isf32) + ldin(bhh, tid, isf32);
        #pragma unroll
        for (int r = 0; r < 4; r++)
            g2[0][r][tid] = ((g2[0][r][tid] + g2[1][r][tid])
                           + (g2[2][r][tid] + g2[3][r][tid])) + bb;
    }
    __syncthreads();
    // phase D: LSTM cell + output (4 rows x 64 lanes)
    if (tid < 256) {
        int row = tid >> 6, u = tid & 63;
        int grow = r0 + row;
        float gi = g2[0][row][u];
        float gf = g2[0][row][64 + u];
        float gg = g2[0][row][128 + u];
        float go = g2[0][row][192 + u];
        float c  = c_ws[grow * 64 + u];
        float si = 1.f / (1.f + __expf(-gi));
        float sf = 1.f / (1.f + __expf(-gf));
        float so = 1.f / (1.f + __expf(-go));
        float cn = sf * c + si * tanhf(gg);
        float hn = so * tanhf(cn);
        c_ws[grow * 64 + u] = cn;
        h_ws[grow * 64 + u] = hn;
        float p0 = hn * ldin(Wout, u * 2 + 0, isf32);
        float p1 = hn * ldin(Wout, u * 2 + 1, isf32);
        #pragma unroll
        for (int o = 32; o >= 1; o >>= 1) {
            p0 += __shfl_xor(p0, o);
            p1 += __shfl_xor(p1, o);
        }
        if (u == 0) {
            int m = masks[t * 1024 + grow];
            float o0 = 0.f, o1 = 0.f;
            if (m != 0) {
                bool appear = (t > 3) && (masks[(t - 3) * 1024 + grow] == 0);
                if (appear) {
                    o0 = ldin(Y, (t * 1024 + grow) * 2 + 0, isf32);
                    o1 = ldin(Y, (t * 1024 + grow) * 2 + 1, isf32);
                } else {
                    o0 = p0 + ldin(bout, 0, isf32);
                    o1 = p1 + ldin(bout, 1, isf32);
                }
            }
            if (!(o0 == o0)) o0 = 0.f;            // sanitize: finite diagnostics
            if (!(o1 == o1)) o1 = 0.f;
            int ofs = (t * 1024 + grow) * 2;
            if (isf32) {
                ((float*)out)[ofs + 0] = o0;
                ((float*)out)[ofs + 1] = o1;
            } else {
                ((unsigned short*)out)[ofs + 0] = f2b(o0);
                ((unsigned short*)out)[ofs + 1] = f2b(o1);
            }
        }
    }
}

extern "C" void kernel_launch(void* const* d_in, const int* in_sizes, int n_in,
                              void* d_out, int out_size, void* d_ws, size_t ws_size,
                              hipStream_t stream) {
    (void)in_sizes; (void)n_in; (void)out_size; (void)ws_size;
    const void* X     = d_in[0];
    const int*  masks = (const int*)d_in[1];
    const void* h0    = d_in[2];
    const void* c0    = d_in[3];
    const void* Y     = d_in[4];
    // d_in[5] = T_obs (unused by reference)
    const int*  Tpred = (const int*)d_in[6];
    const void* Wemb  = d_in[7];
    const void* bemb  = d_in[8];
    const void* Wsoc  = d_in[9];
    const void* bsoc  = d_in[10];
    const void* Wih   = d_in[11];
    const void* bih   = d_in[12];
    const void* Whh   = d_in[13];
    const void* bhh   = d_in[14];
    const void* Wout  = d_in[15];
    const void* bout  = d_in[16];

    char* ws = (char*)d_ws;
    float*          h_ws  = (float*)(ws + 0);
    float*          c_ws  = (float*)(ws + 262144);
    unsigned short* Wt2   = (unsigned short*)(ws + 1835008);
    unsigned short* Hbuf  = (unsigned short*)(ws + 3932160);
    int*            flag  = (int*)(ws + 11141120);
    float*          part  = (float*)(ws + 16777216);
    float*          r_all = (float*)(ws + 33554432);
    unsigned short* offs  = (unsigned short*)(ws + 41943040);
    unsigned short* ents  = (unsigned short*)(ws + 50331648);

    k_detect<<<1, 256, 0, stream>>>(Wsoc, flag);
    k_transpose<<<128, 256, 0, stream>>>(Wsoc, Wt2, flag);
    k_init<<<304, 256, 0, stream>>>(d_out, h0, c0, h_ws, c_ws, Hbuf, flag);
    k_codes<<<8192, 256, 0, stream>>>(X, masks, Wemb, bemb, Tpred, flag,
                                      r_all, offs, ents);
    for (int t = 0; t < 32; t++) {
        k_pool<<<1024, 256, 0, stream>>>(masks, Tpred, h_ws, offs, ents, Hbuf, t);
        k_gemm<<<512, 256, 0, stream>>>(Hbuf, Wt2, Tpred, part, t);
        k_cell<<<256, 1024, 0, stream>>>(masks, Y, bsoc, Wih, bih, Whh, bhh,
                                         Wout, bout, Tpred, flag, h_ws, c_ws,
                                         r_all, part, d_out, t);
    }
}

// Round 13
// 1043.388 us; speedup vs baseline: 1.0572x; 1.0028x over previous
//
#include <hip/hip_runtime.h>
#include <hip/hip_bf16.h>

// SocialLSTM forward, MI355X gfx950.
// Dual-dtype: float inputs may be bf16 or f32; detected at runtime from W_soc.
// ws layout (bytes):
//   h_ws  f32[1024*64]      @ 0
//   c_ws  f32[1024*64]      @ 262144
//   Wt2   bf16[64][256][64] @ 1835008   (W_soc cell-major: [cell][n][k], 2 MB)
//   Hbuf  bf16[1024*3136]   @ 3932160   (49 reachable cells * 64 hid per row)
//   flag  int32             @ 11141120  (0 = bf16 inputs, 1 = f32 inputs)
//   part  f32[8][1024*256]  @ 16777216  (K-split GEMM partials, no atomics)
//   r_all f32[32][1024][64] @ 33554432  (precomputed r = relu(coords@Wemb+b))
//   offs  u16[32*1024][64]  @ 41943040  (per (t,i): 50 prefix offsets of cell lists)
//   ents  u16[32*1024][1024]@ 50331648  (per (t,i): compacted neighbor j-lists)

typedef short bf16x8 __attribute__((ext_vector_type(8)));
typedef float f32x4 __attribute__((ext_vector_type(4)));

__device__ __forceinline__ float u2f(unsigned short u) {
    union { unsigned int i; float f; } v; v.i = ((unsigned int)u) << 16; return v.f;
}
__device__ __forceinline__ unsigned short f2b(float f) {
    __hip_bfloat16 hb = __float2bfloat16(f);
    return *(unsigned short*)&hb;
}
__device__ __forceinline__ float ldin(const void* p, int idx, int isf32) {
    return isf32 ? ((const float*)p)[idx] : u2f(((const unsigned short*)p)[idx]);
}
__device__ __forceinline__ int get_tpred(const int* p) {
    int v = p[0];
    if (v >= 0 && v <= 64) return v;
    float f = ((const float*)p)[0];
    if (f >= 0.f && f <= 64.f) return (int)f;
    float g = u2f(((const unsigned short*)p)[0]);
    if (g >= 0.f && g <= 64.f) return (int)g;
    return 31;
}

// ---------------- dtype detector: bf16-decode W_soc, look for huge/NaN -----
__global__ __launch_bounds__(256) void k_detect(const void* __restrict__ Wsoc,
                                                int* __restrict__ flag) {
    __shared__ int f;
    int tid = threadIdx.x;
    if (tid == 0) f = 0;
    __syncthreads();
    const unsigned short* p = (const unsigned short*)Wsoc;
    #pragma unroll
    for (int k = 0; k < 4; k++) {
        float v = u2f(p[tid * 4 + k]);
        if (!(v == v) || fabsf(v) > 1e20f) f = 1;   // same-address LDS write, benign
    }
    __syncthreads();
    if (tid == 0) flag[0] = f;
}

// ------- one-time: W_soc (4096x256) -> Wt2 bf16 cell-major [cell][n][k] ----
__global__ __launch_bounds__(256) void k_transpose(const void* __restrict__ Wsoc,
                                                   unsigned short* __restrict__ Wt2,
                                                   const int* __restrict__ flag) {
    __shared__ __align__(16) unsigned short tile[32 * 264];
    int isf32 = flag[0];
    int b = blockIdx.x, tid = threadIdx.x;
    int k0 = b * 32;
    if (isf32) {
        const float* W = (const float*)Wsoc;
        #pragma unroll
        for (int p = 0; p < 4; p++) {
            int kk = (tid >> 5) + p * 8;
            int n8 = (tid & 31) * 8;
            #pragma unroll
            for (int q = 0; q < 8; q++)
                tile[kk * 264 + n8 + q] = f2b(W[(k0 + kk) * 256 + n8 + q]);
        }
    } else {
        const unsigned short* W = (const unsigned short*)Wsoc;
        #pragma unroll
        for (int p = 0; p < 4; p++) {
            int kk = (tid >> 5) + p * 8;
            int n8 = (tid & 31) * 8;
            *(uint4*)&tile[kk * 264 + n8] = *(const uint4*)(W + (k0 + kk) * 256 + n8);
        }
    }
    __syncthreads();
    int n = tid;
    unsigned int packed[16];
    #pragma unroll
    for (int q = 0; q < 16; q++) {
        unsigned int lo = tile[(2 * q) * 264 + n];
        unsigned int hi = tile[(2 * q + 1) * 264 + n];
        packed[q] = lo | (hi << 16);
    }
    int craw = k0 >> 6, kk0 = k0 & 63;
    uint4* dst = (uint4*)(Wt2 + (long)craw * 16384 + (long)n * 64 + kk0);
    #pragma unroll
    for (int p = 0; p < 4; p++)
        dst[p] = make_uint4(packed[4*p], packed[4*p+1], packed[4*p+2], packed[4*p+3]);
}

// --------- one-time: zero d_out + Hbuf, h0/c0 -> f32 (grid 304) ------------
__global__ __launch_bounds__(256) void k_init(void* __restrict__ out,
                                              const void* __restrict__ hin,
                                              const void* __restrict__ cin,
                                              float* __restrict__ h_ws,
                                              float* __restrict__ c_ws,
                                              unsigned short* __restrict__ Hbuf,
                                              const int* __restrict__ flag) {
    int isf32 = flag[0];
    int b = blockIdx.x, tid = threadIdx.x;
    if (b < 16) {
        uint4 z = make_uint4(0u, 0u, 0u, 0u);
        uint4* p = (uint4*)out;
        int n16 = isf32 ? 16384 : 8192;          // 65536 elems * 4 or 2 bytes / 16
        for (int idx = b * 256 + tid; idx < n16; idx += 4096) p[idx] = z;
    } else if (b < 48) {
        int sb = b - 16;
        const void* src = (sb < 16) ? hin : cin;
        float* dst = (sb < 16) ? h_ws : c_ws;
        sb &= 15;
        int base = (sb * 256 + tid) * 16;
        #pragma unroll
        for (int p = 0; p < 16; p++) dst[base + p] = ldin(src, base + p, isf32);
    } else {
        // zero Hbuf once: 1024*3136*2B = 401408 uint4. k_pool then only
        // re-zeros rows on active->inactive transitions.
        uint4 z = make_uint4(0u, 0u, 0u, 0u);
        uint4* p = (uint4*)Hbuf;
        for (int idx = (b - 48) * 256 + tid; idx < 401408; idx += 65536)
            p[idx] = z;
    }
}

// ---------------- one-time: codes, 4 agents/block, single merged pass ------
// grid 8192: t = bid>>8, agents i = (bid&255)*4 .. +3. (R11-verified.)
__global__ __launch_bounds__(256) void k_codes(const void* __restrict__ X,
                                               const int* __restrict__ masks,
                                               const void* __restrict__ Wemb,
                                               const void* __restrict__ bemb,
                                               const int* __restrict__ Tpred,
                                               const int* __restrict__ flag,
                                               float* __restrict__ r_all,
                                               unsigned short* __restrict__ offs,
                                               unsigned short* __restrict__ ents) {
    int bid = blockIdx.x;
    int t = bid >> 8, ig = bid & 255;
    if (t > get_tpred(Tpred)) return;
    int isf32 = flag[0];
    int tid = threadIdx.x;
    __shared__ float sx[1024], sy[1024];
    __shared__ unsigned char sm[1024];
    __shared__ int cnt[4][52];
    __shared__ unsigned short off_s[4][52];
    const int* mrow = masks + t * 1024;
    #pragma unroll
    for (int p = 0; p < 4; p++) {
        int j = tid + p * 256;
        sm[j] = (unsigned char)(mrow[j] != 0);
        float x, y;
        if (isf32) {
            float2 xy = *(const float2*)((const float*)X + ((long)(t * 1024 + j)) * 4 + 2);
            x = xy.x; y = xy.y;
        } else {
            unsigned int u = *(const unsigned int*)((const unsigned short*)X + ((long)(t * 1024 + j)) * 4 + 2);
            x = u2f((unsigned short)(u & 0xFFFF));
            y = u2f((unsigned short)(u >> 16));
        }
        sx[j] = x; sy[j] = y;
    }
    if (tid < 208) ((int*)cnt)[tid] = 0;      // 4*52
    __syncthreads();
    {   // r = relu(coords@Wemb + bemb) for the 4 agents (thread a=tid>>6,u=tid&63)
        int a = tid >> 6, u = tid & 63;
        int i = ig * 4 + a;
        float v = ldin(Wemb, u, isf32) * sx[i] + ldin(Wemb, 64 + u, isf32) * sy[i]
                + ldin(bemb, u, isf32);
        r_all[((long)t * 1024 + i) * 64 + u] = fmaxf(v, 0.f);
    }
    float cix[4], ciy[4];
    int act[4];
    #pragma unroll
    for (int a = 0; a < 4; a++) {
        int i = ig * 4 + a;
        act[a] = sm[i];
        cix[a] = sx[i]; ciy[a] = sy[i];
    }
    signed char cc[16];
    unsigned short rk[16];
    #pragma unroll
    for (int p = 0; p < 4; p++) {
        int j = tid + p * 256;
        int smj = sm[j];
        float xj = sx[j], yj = sy[j];
        #pragma unroll
        for (int a = 0; a < 4; a++) {
            int idx = a * 4 + p;
            cc[idx] = -1;
            if (act[a] && smj && j != (ig * 4 + a)) {
                float dx = xj - cix[a], dy = yj - ciy[a];
                int g0 = (int)dx, g1 = (int)dy;   // trunc toward zero == jnp.trunc
                if (g0 >= -3 && g0 <= 3 && g1 >= -3 && g1 <= 3) {
                    int c = (g0 + 3) * 7 + (g1 + 3);      // dense 0..48
                    cc[idx] = (signed char)c;
                    rk[idx] = (unsigned short)atomicAdd(&cnt[a][c], 1);
                }
            }
        }
    }
    __syncthreads();
    {   // 4 parallel wave-scans: wave wv computes agent wv's exclusive prefix
        int wv = tid >> 6, ln = tid & 63;
        int v = (ln < 49) ? cnt[wv][ln] : 0;
        int x = v;
        #pragma unroll
        for (int o = 1; o < 64; o <<= 1) {
            int y = __shfl_up(x, o);
            if (ln >= o) x += y;
        }
        if (ln < 49) off_s[wv][ln] = (unsigned short)(x - v);
        if (ln == 48) off_s[wv][49] = (unsigned short)x;
    }
    __syncthreads();
    #pragma unroll
    for (int a = 0; a < 4; a++) {
        unsigned short* eb = ents + ((long)t * 1024 + ig * 4 + a) * 1024;
        #pragma unroll
        for (int p = 0; p < 4; p++) {
            int idx = a * 4 + p;
            if (cc[idx] >= 0)
                eb[off_s[a][cc[idx]] + rk[idx]] = (unsigned short)(tid + p * 256);
        }
    }
    if (tid < 200) {   // offs for all 4 agents (masked agents get zeros, unread)
        int a = tid / 50, ix = tid - a * 50;
        offs[((long)t * 1024 + ig * 4 + a) * 64 + ix] = off_s[a][ix];
    }
}

// ---------------- per step: pure gather-accumulate pooling -> Hbuf ---------
// 1024 blocks (one per agent). Inactive agents: Hbuf row already zero unless
// the agent was ACTIVE at t-1 (active agents rewrite all 49 cells each step;
// k_init pre-zeroes Hbuf). Zero-fill only on active->inactive transitions.
__global__ __launch_bounds__(256) void k_pool(const int* __restrict__ masks,
                                              const int* __restrict__ Tpred,
                                              const float* __restrict__ h_ws,
                                              const unsigned short* __restrict__ offs,
                                              const unsigned short* __restrict__ ents,
                                              unsigned short* __restrict__ Hbuf,
                                              int t) {
    if (t > get_tpred(Tpred)) return;
    int i = blockIdx.x, tid = threadIdx.x;
    long hb_base = (long)i * 3136;
    if (masks[t * 1024 + i] == 0) {
        if (t == 0 || masks[(t - 1) * 1024 + i] == 0) return;  // already zero
        unsigned int* hp = (unsigned int*)(Hbuf + hb_base);    // clear stale row
        for (int idx = tid; idx < 1568; idx += 256) hp[idx] = 0u;
        return;
    }
    __shared__ __align__(16) unsigned short el[1024];
    __shared__ unsigned short of[52];
    if (tid < 50) of[tid] = offs[((long)t * 1024 + i) * 64 + tid];
    {
        const uint4* src = (const uint4*)(ents + ((long)t * 1024 + i) * 1024);
        uint4* dst = (uint4*)el;
        if (tid < 128) dst[tid] = src[tid];   // stage full list; tail garbage unread
    }
    __syncthreads();
    int w = tid >> 6, lane = tid & 63;
    for (int c = w; c < 49; c += 4) {       // round-robin cells over 4 waves
        int k = of[c], n = of[c + 1];
        float acc = 0.f;
        for (; k + 8 <= n; k += 8) {        // 8 loads in flight per group
            int j0 = el[k], j1 = el[k + 1], j2 = el[k + 2], j3 = el[k + 3];
            int j4 = el[k + 4], j5 = el[k + 5], j6 = el[k + 6], j7 = el[k + 7];
            float v0 = h_ws[j0 * 64 + lane];
            float v1 = h_ws[j1 * 64 + lane];
            float v2 = h_ws[j2 * 64 + lane];
            float v3 = h_ws[j3 * 64 + lane];
            float v4 = h_ws[j4 * 64 + lane];
            float v5 = h_ws[j5 * 64 + lane];
            float v6 = h_ws[j6 * 64 + lane];
            float v7 = h_ws[j7 * 64 + lane];
            acc += ((v0 + v1) + (v2 + v3)) + ((v4 + v5) + (v6 + v7));
        }
        for (; k < n; k++) acc += h_ws[el[k] * 64 + lane];
        Hbuf[hb_base + c * 64 + lane] = f2b(acc);
    }
}

// ---------------- per step: part[s] = H @ W_soc slice (MFMA, dbuf LDS) -----
// grid 512: ch = bid&3 (64-col slice), s = (bid>>2)&7 (K-split), rb = bid>>5.
// B-tile staged from cell-major Wt2: fully contiguous per cell. (R4-verified.)
__global__ __launch_bounds__(256) void k_gemm(const unsigned short* __restrict__ Hbuf,
                                              const unsigned short* __restrict__ Wt2,
                                              const int* __restrict__ Tpred,
                                              float* __restrict__ part,
                                              int t) {
    if (t > get_tpred(Tpred)) return;
    int bid = blockIdx.x, tid = threadIdx.x;
    int ch = bid & 3, s = (bid >> 2) & 7, rb = bid >> 5;
    int row0 = rb * 64, col0 = ch * 64;
    int m0 = (49 * s) >> 3, m1 = (49 * (s + 1)) >> 3;   // 6,6,6,6,6,6,6,7 cells
    __shared__ __align__(16) short Asm[2][64 * 72];   // double-buffered
    __shared__ __align__(16) short Bsm[2][64 * 72];
    int w = tid >> 6, lane = tid & 63;
    int wrow = (w & 1) * 32, wcol = (w >> 1) * 32;
    int mrow = lane & 15, q = lane >> 4;
    int row = tid >> 2, seg = tid & 3;
    const unsigned short* Arow = Hbuf + (long)(row0 + row) * 3136;
    const long boff = (long)(col0 + row) * 64;
    f32x4 acc[2][2];
    f32x4 zz = {0.f, 0.f, 0.f, 0.f};
    #pragma unroll
    for (int a = 0; a < 2; a++)
        #pragma unroll
        for (int b = 0; b < 2; b++) acc[a][b] = zz;
    uint4 ra0, ra1, rb0, rb1;
    {   // prologue: load cell m0
        int craw = ((m0 / 7) * 8 + (m0 % 7) + 9);
        const unsigned short* Bc = Wt2 + (long)craw * 16384 + boff;
        ra0 = *(const uint4*)(Arow + m0 * 64 + seg * 8);
        ra1 = *(const uint4*)(Arow + m0 * 64 + (seg + 4) * 8);
        rb0 = *(const uint4*)(Bc + seg * 8);
        rb1 = *(const uint4*)(Bc + (seg + 4) * 8);
        *(uint4*)&Asm[0][row * 72 + seg * 8] = ra0;
        *(uint4*)&Asm[0][row * 72 + (seg + 4) * 8] = ra1;
        *(uint4*)&Bsm[0][row * 72 + seg * 8] = rb0;
        *(uint4*)&Bsm[0][row * 72 + (seg + 4) * 8] = rb1;
    }
    __syncthreads();
    for (int m = m0; m < m1; m++) {
        int p = (m - m0) & 1;
        if (m + 1 < m1) {   // prefetch next cell into the other buffer
            int mm = m + 1;
            int craw = ((mm / 7) * 8 + (mm % 7) + 9);
            const unsigned short* Bc = Wt2 + (long)craw * 16384 + boff;
            ra0 = *(const uint4*)(Arow + mm * 64 + seg * 8);
            ra1 = *(const uint4*)(Arow + mm * 64 + (seg + 4) * 8);
            rb0 = *(const uint4*)(Bc + seg * 8);
            rb1 = *(const uint4*)(Bc + (seg + 4) * 8);
            *(uint4*)&Asm[p ^ 1][row * 72 + seg * 8] = ra0;
            *(uint4*)&Asm[p ^ 1][row * 72 + (seg + 4) * 8] = ra1;
            *(uint4*)&Bsm[p ^ 1][row * 72 + seg * 8] = rb0;
            *(uint4*)&Bsm[p ^ 1][row * 72 + (seg + 4) * 8] = rb1;
        }
        #pragma unroll
        for (int kc = 0; kc < 2; kc++) {
            bf16x8 a0 = *(bf16x8*)&Asm[p][(wrow +      mrow) * 72 + kc * 32 + q * 8];
            bf16x8 a1 = *(bf16x8*)&Asm[p][(wrow + 16 + mrow) * 72 + kc * 32 + q * 8];
            #pragma unroll
            for (int ct = 0; ct < 2; ct++) {
                bf16x8 bv = *(bf16x8*)&Bsm[p][(wcol + ct * 16 + mrow) * 72 + kc * 32 + q * 8];
                acc[0][ct] = __builtin_amdgcn_mfma_f32_16x16x32_bf16(a0, bv, acc[0][ct], 0, 0, 0);
                acc[1][ct] = __builtin_amdgcn_mfma_f32_16x16x32_bf16(a1, bv, acc[1][ct], 0, 0, 0);
            }
        }
        __syncthreads();
    }
    // C/D layout: col = lane&15, row = (lane>>4)*4 + reg. Plain stores, no RMW.
    float* ps = part + (long)s * 262144;
    #pragma unroll
    for (int rt = 0; rt < 2; rt++)
        #pragma unroll
        for (int ct = 0; ct < 2; ct++)
            #pragma unroll
            for (int r = 0; r < 4; r++) {
                int grow = row0 + wrow + rt * 16 + q * 4 + r;
                int gcol = col0 + wcol + ct * 16 + mrow;
                ps[grow * 256 + gcol] = acc[rt][ct][r];
            }
}

// ---------------- per step: gates GEMV, LSTM cell, out ---------------------
// grid 256 x 1024 threads: 4 rows/block, 4-way K-split (96 k-iters each).
// 16 waves/CU + unroll-8 load pipelining. Phase C folded into phase D
// (one fewer barrier + LDS round-trip; identical arithmetic order).
__global__ __launch_bounds__(1024) void k_cell(const int* __restrict__ masks,
                                               const void* __restrict__ Y,
                                               const void* __restrict__ bsoc,
                                               const void* __restrict__ Wih,
                                               const void* __restrict__ bih,
                                               const void* __restrict__ Whh,
                                               const void* __restrict__ bhh,
                                               const void* __restrict__ Wout,
                                               const void* __restrict__ bout,
                                               const int* __restrict__ Tpred,
                                               const int* __restrict__ flag,
                                               float* __restrict__ h_ws,
                                               float* __restrict__ c_ws,
                                               const float* __restrict__ r_all,
                                               const float* __restrict__ part,
                                               void* __restrict__ out,
                                               int t) {
    if (t > get_tpred(Tpred)) return;
    int isf32 = flag[0];
    int tid = threadIdx.x;
    int r0 = blockIdx.x * 4;
    __shared__ __align__(16) float zT[384][4];   // z transposed: [k][local row]
    __shared__ float g2[4][4][256];              // [ksplit][row][col] partials
    // phase A: build zT = [r | e | h] for the block's 4 rows
    for (int idx = tid; idx < 1536; idx += 1024) {
        int r = idx / 384, k = idx - r * 384;
        int grow = r0 + r;
        float v;
        if (k < 64) {
            v = r_all[((long)t * 1024 + grow) * 64 + k];
        } else if (k < 320) {
            int col = k - 64;
            const float* pp = part + grow * 256 + col;
            float s0 = pp[0 * 262144] + pp[1 * 262144];
            float s1 = pp[2 * 262144] + pp[3 * 262144];
            float s2 = pp[4 * 262144] + pp[5 * 262144];
            float s3 = pp[6 * 262144] + pp[7 * 262144];
            v = fmaxf(ldin(bsoc, col, isf32) + ((s0 + s1) + (s2 + s3)), 0.f);
        } else {
            v = h_ws[grow * 64 + (k - 320)];
        }
        zT[k][r] = v;
    }
    __syncthreads();
    // phase B: partial gates; dtype branch hoisted, unroll-8 load pipelining
    int kh = tid >> 8, col = tid & 255;
    int klo = kh * 96, khi = klo + 96;
    float a0 = 0.f, a1 = 0.f, a2 = 0.f, a3 = 0.f;
    if (isf32) {
        const float* W1 = (const float*)Wih;
        const float* W2 = (const float*)Whh;
        int kmid = khi < 320 ? khi : 320;
        #pragma unroll 8
        for (int k = klo; k < kmid; k++) {
            float wv = W1[(long)k * 256 + col];
            f32x4 zv = *(f32x4*)&zT[k][0];
            a0 += zv[0] * wv; a1 += zv[1] * wv; a2 += zv[2] * wv; a3 += zv[3] * wv;
        }
        int k2 = klo > 320 ? klo : 320;
        #pragma unroll 8
        for (int k = k2; k < khi; k++) {
            float wv = W2[(long)(k - 320) * 256 + col];
            f32x4 zv = *(f32x4*)&zT[k][0];
            a0 += zv[0] * wv; a1 += zv[1] * wv; a2 += zv[2] * wv; a3 += zv[3] * wv;
        }
    } else {
        const unsigned short* W1 = (const unsigned short*)Wih;
        const unsigned short* W2 = (const unsigned short*)Whh;
        int kmid = khi < 320 ? khi : 320;
        #pragma unroll 8
        for (int k = klo; k < kmid; k++) {
            float wv = u2f(W1[(long)k * 256 + col]);
            f32x4 zv = *(f32x4*)&zT[k][0];
            a0 += zv[0] * wv; a1 += zv[1] * wv; a2 += zv[2] * wv; a3 += zv[3] * wv;
        }
        int k2 = klo > 320 ? klo : 320;
        #pragma unroll 8
        for (int k = k2; k < khi; k++) {
            float wv = u2f(W2[(long)(k - 320) * 256 + col]);
            f32x4 zv = *(f32x4*)&zT[k][0];
            a0 += zv[0] * wv; a1 += zv[1] * wv; a2 += zv[2] * wv; a3 += zv[3] * wv;
        }
    }
    g2[kh][0][col] = a0; g2[kh][1][col] = a1;
    g2[kh][2][col] = a2; g2[kh][3][col] = a3;
    __syncthreads();
    // phase D: fold K-split partials inline + LSTM cell + output (4x64 lanes)
    if (tid < 256) {
        int row = tid >> 6, u = tid & 63;
        int grow = r0 + row;
        float gi, gf, gg, go;
        {
            float bb = ldin(bih, u, isf32) + ldin(bhh, u, isf32);
            gi = ((g2[0][row][u] + g2[1][row][u])
                + (g2[2][row][u] + g2[3][row][u])) + bb;
        }
        {
            int cix = 64 + u;
            float bb = ldin(bih, cix, isf32) + ldin(bhh, cix, isf32);
            gf = ((g2[0][row][cix] + g2[1][row][cix])
                + (g2[2][row][cix] + g2[3][row][cix])) + bb;
        }
        {
            int cix = 128 + u;
            float bb = ldin(bih, cix, isf32) + ldin(bhh, cix, isf32);
            gg = ((g2[0][row][cix] + g2[1][row][cix])
                + (g2[2][row][cix] + g2[3][row][cix])) + bb;
        }
        {
            int cix = 192 + u;
            float bb = ldin(bih, cix, isf32) + ldin(bhh, cix, isf32);
            go = ((g2[0][row][cix] + g2[1][row][cix])
                + (g2[2][row][cix] + g2[3][row][cix])) + bb;
        }
        float c  = c_ws[grow * 64 + u];
        float si = 1.f / (1.f + __expf(-gi));
        float sf = 1.f / (1.f + __expf(-gf));
        float so = 1.f / (1.f + __expf(-go));
        float cn = sf * c + si * tanhf(gg);
        float hn = so * tanhf(cn);
        c_ws[grow * 64 + u] = cn;
        h_ws[grow * 64 + u] = hn;
        float p0 = hn * ldin(Wout, u * 2 + 0, isf32);
        float p1 = hn * ldin(Wout, u * 2 + 1, isf32);
        #pragma unroll
        for (int o = 32; o >= 1; o >>= 1) {
            p0 += __shfl_xor(p0, o);
            p1 += __shfl_xor(p1, o);
        }
        if (u == 0) {
            int m = masks[t * 1024 + grow];
            float o0 = 0.f, o1 = 0.f;
            if (m != 0) {
                bool appear = (t > 3) && (masks[(t - 3) * 1024 + grow] == 0);
                if (appear) {
                    o0 = ldin(Y, (t * 1024 + grow) * 2 + 0, isf32);
                    o1 = ldin(Y, (t * 1024 + grow) * 2 + 1, isf32);
                } else {
                    o0 = p0 + ldin(bout, 0, isf32);
                    o1 = p1 + ldin(bout, 1, isf32);
                }
            }
            if (!(o0 == o0)) o0 = 0.f;            // sanitize: finite diagnostics
            if (!(o1 == o1)) o1 = 0.f;
            int ofs = (t * 1024 + grow) * 2;
            if (isf32) {
                ((float*)out)[ofs + 0] = o0;
                ((float*)out)[ofs + 1] = o1;
            } else {
                ((unsigned short*)out)[ofs + 0] = f2b(o0);
                ((unsigned short*)out)[ofs + 1] = f2b(o1);
            }
        }
    }
}

extern "C" void kernel_launch(void* const* d_in, const int* in_sizes, int n_in,
                              void* d_out, int out_size, void* d_ws, size_t ws_size,
                              hipStream_t stream) {
    (void)in_sizes; (void)n_in; (void)out_size; (void)ws_size;
    const void* X     = d_in[0];
    const int*  masks = (const int*)d_in[1];
    const void* h0    = d_in[2];
    const void* c0    = d_in[3];
    const void* Y     = d_in[4];
    // d_in[5] = T_obs (unused by reference)
    const int*  Tpred = (const int*)d_in[6];
    const void* Wemb  = d_in[7];
    const void* bemb  = d_in[8];
    const void* Wsoc  = d_in[9];
    const void* bsoc  = d_in[10];
    const void* Wih   = d_in[11];
    const void* bih   = d_in[12];
    const void* Whh   = d_in[13];
    const void* bhh   = d_in[14];
    const void* Wout  = d_in[15];
    const void* bout  = d_in[16];

    char* ws = (char*)d_ws;
    float*          h_ws  = (float*)(ws + 0);
    float*          c_ws  = (float*)(ws + 262144);
    unsigned short* Wt2   = (unsigned short*)(ws + 1835008);
    unsigned short* Hbuf  = (unsigned short*)(ws + 3932160);
    int*            flag  = (int*)(ws + 11141120);
    float*          part  = (float*)(ws + 16777216);
    float*          r_all = (float*)(ws + 33554432);
    unsigned short* offs  = (unsigned short*)(ws + 41943040);
    unsigned short* ents  = (unsigned short*)(ws + 50331648);

    k_detect<<<1, 256, 0, stream>>>(Wsoc, flag);
    k_transpose<<<128, 256, 0, stream>>>(Wsoc, Wt2, flag);
    k_init<<<304, 256, 0, stream>>>(d_out, h0, c0, h_ws, c_ws, Hbuf, flag);
    k_codes<<<8192, 256, 0, stream>>>(X, masks, Wemb, bemb, Tpred, flag,
                                      r_all, offs, ents);
    for (int t = 0; t < 32; t++) {
        k_pool<<<1024, 256, 0, stream>>>(masks, Tpred, h_ws, offs, ents, Hbuf, t);
        k_gemm<<<512, 256, 0, stream>>>(Hbuf, Wt2, Tpred, part, t);
        k_cell<<<256, 1024, 0, stream>>>(masks, Y, bsoc, Wih, bih, Whh, bhh,
                                         Wout, bout, Tpred, flag, h_ws, c_ws,
                                         r_all, part, d_out, t);
    }
}